// Round 24
// baseline (446.163 us; speedup 1.0000x reference)
//
#include <hip/hip_runtime.h>
#include <cstddef>
#include <cstdint>

#define B_    256
#define SX_   256
#define SY_   70
#define F_    512
#define EMB_  256
#define NY_   (B_*SY_)     // 17920
#define NE_   (4*B_*SY_)   // 71680

typedef short s16x8 __attribute__((ext_vector_type(8)));   // MFMA A/B frag (8 bf16)
typedef float f32x4 __attribute__((ext_vector_type(4)));   // MFMA C/D frag
typedef unsigned short us4 __attribute__((ext_vector_type(4)));
typedef unsigned short us8 __attribute__((ext_vector_type(8)));

__device__ __forceinline__ unsigned short f2bf(float f) {
    unsigned u = __builtin_bit_cast(unsigned, f);
    u += 0x7fffu + ((u >> 16) & 1u);          // RNE
    return (unsigned short)(u >> 16);
}
__device__ __forceinline__ float bf2f(unsigned short b) {
    unsigned u = ((unsigned)b) << 16;
    return __builtin_bit_cast(float, u);
}

// ---------------------------------------------------------------------------
// Unified bf16 MFMA GEMM, C = A @ Bt^T. A:[M][K] bf16, Bt:[N][K] bf16.
// 128x128 tile, BK=64, 4 waves (2x2 of 64x64), 16x16x32 MFMA.
// SWZ: 1 = flattened 1D grid with bijective XCD remap (gridDim.x % 8 == 0).
// ---------------------------------------------------------------------------
template<int SWZ>
__global__ __launch_bounds__(256, 2)
void gemm_mfma(const unsigned short* __restrict__ A, int lda, long sAb,
               const unsigned short* __restrict__ Bt, int ldb, long sBb,
               float* __restrict__ Cf, int ldc, long sCfb,
               unsigned short* __restrict__ Cb, int ldcb, long sCbb,
               int M, int K, float scale, int nx, int ny)
{
    __shared__ unsigned short As[128 * 64];
    __shared__ unsigned short Bs[128 * 64];
    char* AsB = (char*)As;
    char* BsB = (char*)Bs;
    const int tid = threadIdx.x;
    int bxi, byi, z;
    if (SWZ) {
        const int nwg = gridDim.x;
        const int bid = blockIdx.x;
        const int wg = (bid & 7) * (nwg >> 3) + (bid >> 3);
        bxi = wg % nx;
        byi = (wg / nx) % ny;
        z   = wg / (nx * ny);
    } else {
        bxi = blockIdx.x; byi = blockIdx.y; z = blockIdx.z;
    }
    A  += (size_t)z * sAb;
    Bt += (size_t)z * sBb;
    const int bm = byi * 128, bn = bxi * 128;
    const int lane = tid & 63;
    const int w = tid >> 6, wr = w >> 1, wc = w & 1;
    const int l15 = lane & 15, lq = lane >> 4;

    f32x4 acc[4][4];
    const f32x4 z4 = {0.f, 0.f, 0.f, 0.f};
#pragma unroll
    for (int m = 0; m < 4; ++m)
#pragma unroll
        for (int n = 0; n < 4; ++n) acc[m][n] = z4;

    for (int k0 = 0; k0 < K; k0 += 64) {
#pragma unroll
        for (int i = 0; i < 4; ++i) {
            const int row = i * 32 + (tid >> 3);
            const int k8  = (tid & 7) ^ (row & 7);
            int ra = bm + row; ra = (ra < M) ? ra : (M - 1);
            const unsigned short* g = A + (size_t)ra * lda + k0 + k8 * 8;
            __builtin_amdgcn_global_load_lds(
                (const __attribute__((address_space(1))) unsigned int*)g,
                (__attribute__((address_space(3))) unsigned int*)(AsB + i * 4096 + tid * 16),
                16, 0, 0);
        }
#pragma unroll
        for (int i = 0; i < 4; ++i) {
            const int row = i * 32 + (tid >> 3);
            const int k8  = (tid & 7) ^ (row & 7);
            const unsigned short* g = Bt + (size_t)(bn + row) * ldb + k0 + k8 * 8;
            __builtin_amdgcn_global_load_lds(
                (const __attribute__((address_space(1))) unsigned int*)g,
                (__attribute__((address_space(3))) unsigned int*)(BsB + i * 4096 + tid * 16),
                16, 0, 0);
        }
        __syncthreads();
#pragma unroll
        for (int kk = 0; kk < 2; ++kk) {
            s16x8 af[4], bf[4];
#pragma unroll
            for (int m = 0; m < 4; ++m) {
                const int row = wr * 64 + m * 16 + l15;
                const int slot = (kk * 4 + lq) ^ (row & 7);
                af[m] = *(const s16x8*)(AsB + row * 128 + slot * 16);
            }
#pragma unroll
            for (int n = 0; n < 4; ++n) {
                const int col = wc * 64 + n * 16 + l15;
                const int slot = (kk * 4 + lq) ^ (col & 7);
                bf[n] = *(const s16x8*)(BsB + col * 128 + slot * 16);
            }
#pragma unroll
            for (int m = 0; m < 4; ++m)
#pragma unroll
                for (int n = 0; n < 4; ++n)
                    acc[m][n] = __builtin_amdgcn_mfma_f32_16x16x32_bf16(
                        af[m], bf[n], acc[m][n], 0, 0, 0);
        }
        __syncthreads();
    }

    float* cf = Cf ? Cf + (size_t)z * sCfb : nullptr;
    unsigned short* cb = Cb ? Cb + (size_t)z * sCbb : nullptr;
#pragma unroll
    for (int m = 0; m < 4; ++m) {
#pragma unroll
        for (int n = 0; n < 4; ++n) {
            const int col = bn + wc * 64 + n * 16 + l15;
            f32x4 v = acc[m][n];
#pragma unroll
            for (int r = 0; r < 4; ++r) {
                const int gr = bm + wr * 64 + m * 16 + lq * 4 + r;
                if (gr >= M) continue;
                float o = v[r] * scale;
                if (cf) cf[(size_t)gr * ldc + col] = o;
                if (cb) cb[(size_t)gr * ldcb + col] = f2bf(o);
            }
        }
    }
}

// ---------------------------------------------------------------------------
// Fused attention layer kernel, one block per batch (grid 256, 8 waves).
// Phase 1: S = scale * hb @ xqT^T  (K=256, BK=32, 8 steps, counted-vmcnt
//          pipeline, 3 staging bufs, depth-2 prefetch).
// Middle: softmax; alpha bf16 -> Al (swizzled); vectorized alpha dump.
// Phase 2: O = alpha @ xv; vectorized y dump (y = relu(O + aggb)).
// Phase 3 (LAST): score = y @ lzT + lzb.  Phase 4 (LAST): Y12 = y @ gw.
// ---------------------------------------------------------------------------
template<int LAST>
__global__ __launch_bounds__(512, 1)
void attn_pv(const unsigned short* __restrict__ Hb,   // [17920][256] bf16 (A)
             const unsigned short* __restrict__ XQ,   // [B][256][768], layer col ofs
             const unsigned short* __restrict__ XV,   // [B][768][256] (layer slice)
             long sXVb,
             const unsigned short* __restrict__ aggb, // [17920][256] bf16
             const unsigned short* __restrict__ lzT,  // [256][256] bf16 (LAST)
             const float* __restrict__ lzb,           // [256] f32 (LAST)
             const float* __restrict__ gw,            // [512][8] f32 (LAST)
             float* __restrict__ Y12g,                // [17920][16] f32 (LAST)
             float* __restrict__ Aout,                // [B][70][256]
             unsigned short* __restrict__ Yb,         // [17920][256] bf16
             float* __restrict__ Yf,                  // f32 or null
             float* __restrict__ Score,               // [17920][256] f32 (LAST)
             float scale)
{
    __shared__ unsigned short SB[3 * 12288];  // 72 KB: ph1 3x24KB; ph2/3 2x32KB
    __shared__ unsigned short Al[128 * 256];  // 64 KB (alpha / O / y, swizzled)
    __shared__ float red[4][2][64];
    char* SBb = (char*)SB;
    char* AlB = (char*)Al;
    const int tid = threadIdx.x;
    const int z = blockIdx.x;
    const unsigned short* hbz = Hb + (size_t)z * SY_ * 256;
    const unsigned short* xqz = XQ + (size_t)z * 196608;   // [256 rows][768]
    const unsigned short* xvb = XV + (size_t)z * sXVb;
    const int lane = tid & 63;
    const int w = tid >> 6, wr = w >> 2, wc = w & 3;
    const int l15 = lane & 15, lq = lane >> 4;

    // ---- phase 1: counted-vmcnt pipeline, K=256, BK=32, 8 steps, 3 bufs ----
    // buf: [0,8K) A tile 128x32 (64B rows, slot swz lq^((row>>1)&3));
    //      [8K,24K) B tile 256x32.
    auto stage1 = [&](int t) {
        char* base = SBb + (t % 3) * 24576;
        {
            const int row = tid >> 2;
            const int k8  = (tid & 3) ^ ((row >> 1) & 3);
            const int ra = (row < SY_) ? row : (SY_ - 1);
            const unsigned short* g = hbz + (size_t)ra * 256 + t * 32 + k8 * 8;
            __builtin_amdgcn_global_load_lds(
                (const __attribute__((address_space(1))) unsigned int*)g,
                (__attribute__((address_space(3))) unsigned int*)(base + tid * 16),
                16, 0, 0);
        }
#pragma unroll
        for (int i = 0; i < 2; ++i) {
            const int row = i * 128 + (tid >> 2);
            const int k8  = (tid & 3) ^ ((row >> 1) & 3);
            const unsigned short* g = xqz + (size_t)row * 768 + t * 32 + k8 * 8;
            __builtin_amdgcn_global_load_lds(
                (const __attribute__((address_space(1))) unsigned int*)g,
                (__attribute__((address_space(3))) unsigned int*)(base + 8192 + i * 8192 + tid * 16),
                16, 0, 0);
        }
    };

    f32x4 acc[4][4];
    const f32x4 z4 = {0.f, 0.f, 0.f, 0.f};
#pragma unroll
    for (int m = 0; m < 4; ++m)
#pragma unroll
        for (int n = 0; n < 4; ++n) acc[m][n] = z4;

    stage1(0);
    stage1(1);
    for (int t = 0; t < 8; ++t) {
        if (t + 2 < 8) stage1(t + 2);
        if (t < 6)       asm volatile("s_waitcnt vmcnt(6)" ::: "memory");
        else if (t == 6) asm volatile("s_waitcnt vmcnt(3)" ::: "memory");
        else             asm volatile("s_waitcnt vmcnt(0)" ::: "memory");
        __builtin_amdgcn_s_barrier();
        asm volatile("" ::: "memory");
        char* base = SBb + (t % 3) * 24576;
        s16x8 af[4], bf[4];
#pragma unroll
        for (int m = 0; m < 4; ++m) {
            const int row = wr * 64 + m * 16 + l15;
            const int slot = lq ^ ((row >> 1) & 3);
            af[m] = *(const s16x8*)(base + row * 64 + slot * 16);
        }
#pragma unroll
        for (int n = 0; n < 4; ++n) {
            const int col = wc * 64 + n * 16 + l15;
            const int slot = lq ^ ((col >> 1) & 3);
            bf[n] = *(const s16x8*)(base + 8192 + col * 64 + slot * 16);
        }
#pragma unroll
        for (int m = 0; m < 4; ++m)
#pragma unroll
            for (int n = 0; n < 4; ++n)
                acc[m][n] = __builtin_amdgcn_mfma_f32_16x16x32_bf16(
                    af[m], bf[n], acc[m][n], 0, 0, 0);
        asm volatile("" ::: "memory");
        __builtin_amdgcn_s_barrier();
    }

    // ---- softmax ----
#pragma unroll
    for (int m = 0; m < 4; ++m)
#pragma unroll
        for (int n = 0; n < 4; ++n)
#pragma unroll
            for (int r = 0; r < 4; ++r) acc[m][n][r] *= scale;

    float rmax[4][4];
#pragma unroll
    for (int m = 0; m < 4; ++m)
#pragma unroll
        for (int r = 0; r < 4; ++r) {
            float mx = acc[m][0][r];
#pragma unroll
            for (int n = 1; n < 4; ++n) mx = fmaxf(mx, acc[m][n][r]);
            mx = fmaxf(mx, __shfl_xor(mx, 1));
            mx = fmaxf(mx, __shfl_xor(mx, 2));
            mx = fmaxf(mx, __shfl_xor(mx, 4));
            mx = fmaxf(mx, __shfl_xor(mx, 8));
            rmax[m][r] = mx;
        }
    if (l15 == 0) {
#pragma unroll
        for (int m = 0; m < 4; ++m)
#pragma unroll
            for (int r = 0; r < 4; ++r)
                red[wc][wr][m * 16 + lq * 4 + r] = rmax[m][r];
    }
    __syncthreads();
    float rtot[4][4];
#pragma unroll
    for (int m = 0; m < 4; ++m)
#pragma unroll
        for (int r = 0; r < 4; ++r) {
            const int lr = m * 16 + lq * 4 + r;
            rtot[m][r] = fmaxf(fmaxf(red[0][wr][lr], red[1][wr][lr]),
                               fmaxf(red[2][wr][lr], red[3][wr][lr]));
        }
    __syncthreads();
    float rsum[4][4];
#pragma unroll
    for (int m = 0; m < 4; ++m)
#pragma unroll
        for (int r = 0; r < 4; ++r) {
            float s = 0.f;
#pragma unroll
            for (int n = 0; n < 4; ++n) {
                float e = __expf(acc[m][n][r] - rtot[m][r]);
                acc[m][n][r] = e;
                s += e;
            }
            s += __shfl_xor(s, 1);
            s += __shfl_xor(s, 2);
            s += __shfl_xor(s, 4);
            s += __shfl_xor(s, 8);
            rsum[m][r] = s;
        }
    if (l15 == 0) {
#pragma unroll
        for (int m = 0; m < 4; ++m)
#pragma unroll
            for (int r = 0; r < 4; ++r)
                red[wc][wr][m * 16 + lq * 4 + r] = rsum[m][r];
    }
    __syncthreads();
    // ---- alpha: bf16 -> LDS Al (swizzled) ----
#pragma unroll
    for (int m = 0; m < 4; ++m)
#pragma unroll
        for (int r = 0; r < 4; ++r) {
            const int lr = m * 16 + lq * 4 + r;
            const int row = wr * 64 + lr;
            const float inv = 1.0f / (red[0][wr][lr] + red[1][wr][lr] +
                                      red[2][wr][lr] + red[3][wr][lr]);
#pragma unroll
            for (int n = 0; n < 4; ++n) {
                const int col = wc * 64 + n * 16 + l15;
                *(unsigned short*)(AlB + row * 512 +
                    (((col >> 3) ^ (row & 7)) << 4) + ((col & 7) << 1))
                    = f2bf(acc[m][n][r] * inv);
            }
        }
    __syncthreads();
    // ---- vectorized alpha dump: Al bf16 -> Aout f32 (rows < 70) ----
    {
        float* ao = Aout + (size_t)z * SY_ * SX_;
        for (int idx = tid; idx < SY_ * 8; idx += 512) {
            const int row = idx >> 3, seg = idx & 7;
            float tmp[32];
#pragma unroll
            for (int c8 = 0; c8 < 4; ++c8) {
                const int chunk = seg * 4 + c8;
                us8 v = *(const us8*)(AlB + row * 512 + ((chunk ^ (row & 7)) << 4));
#pragma unroll
                for (int j = 0; j < 8; ++j) tmp[c8 * 8 + j] = bf2f(v[j]);
            }
            float* dst = ao + (size_t)row * SX_ + seg * 32;
#pragma unroll
            for (int q = 0; q < 8; ++q) {
                float4 o4; o4.x = tmp[q*4]; o4.y = tmp[q*4+1];
                o4.z = tmp[q*4+2]; o4.w = tmp[q*4+3];
                ((float4*)dst)[q] = o4;
            }
        }
    }

    // ---- phase 2: O = alpha @ xv  (K = 256, BK=64, dbuf + syncthreads) ----
    char* v_buf[2] = {SBb, SBb + 32768};
    auto stage2 = [&](int k0, int buf, const unsigned short* srcm) {
        char* bb = v_buf[buf];
#pragma unroll
        for (int i = 0; i < 4; ++i) {
            const int row = i * 64 + (tid >> 3);
            const int k8  = (tid & 7) ^ (row & 7);
            const unsigned short* g = srcm + (size_t)row * 256 + k0 + k8 * 8;
            __builtin_amdgcn_global_load_lds(
                (const __attribute__((address_space(1))) unsigned int*)g,
                (__attribute__((address_space(3))) unsigned int*)(bb + i * 8192 + tid * 16),
                16, 0, 0);
        }
    };

    f32x4 oac[4][4];
#pragma unroll
    for (int m = 0; m < 4; ++m)
#pragma unroll
        for (int n = 0; n < 4; ++n) oac[m][n] = z4;

    stage2(0, 0, xvb);
    __syncthreads();
    int cur = 0;
    for (int ks = 0; ks < 4; ++ks) {
        if (ks < 3) stage2((ks + 1) * 64, cur ^ 1, xvb);
        char* bb = v_buf[cur];
        const int k0 = ks * 64;
#pragma unroll
        for (int kk = 0; kk < 2; ++kk) {
            s16x8 af[4], bf[4];
#pragma unroll
            for (int m = 0; m < 4; ++m) {
                const int row = wr * 64 + m * 16 + l15;
                const int chunk = (k0 >> 3) + kk * 4 + lq;
                af[m] = *(const s16x8*)(AlB + row * 512 + ((chunk ^ (row & 7)) << 4));
            }
#pragma unroll
            for (int n = 0; n < 4; ++n) {
                const int col = wc * 64 + n * 16 + l15;
                const int slot = (kk * 4 + lq) ^ (col & 7);
                bf[n] = *(const s16x8*)(bb + col * 128 + slot * 16);
            }
#pragma unroll
            for (int m = 0; m < 4; ++m)
#pragma unroll
                for (int n = 0; n < 4; ++n)
                    oac[m][n] = __builtin_amdgcn_mfma_f32_16x16x32_bf16(
                        af[m], bf[n], oac[m][n], 0, 0, 0);
        }
        __syncthreads();
        cur ^= 1;
    }

    // ---- O bf16 -> Al (rows < 70) ----
#pragma unroll
    for (int m = 0; m < 4; ++m)
#pragma unroll
        for (int n = 0; n < 4; ++n) {
            const int col = wc * 64 + n * 16 + l15;
            f32x4 v = oac[m][n];
#pragma unroll
            for (int r = 0; r < 4; ++r) {
                const int row = wr * 64 + m * 16 + lq * 4 + r;
                if (row >= SY_) continue;
                *(unsigned short*)(AlB + row * 512 +
                    (((col >> 3) ^ (row & 7)) << 4) + ((col & 7) << 1)) = f2bf(v[r]);
            }
        }
    __syncthreads();
    // ---- vectorized y dump: y = relu(O + aggb) -> Yb (+Yf), y -> Al ----
    {
        const size_t nodeBase = (size_t)z * SY_;
        for (int idx = tid; idx < SY_ * 8; idx += 512) {
            const int row = idx >> 3, seg = idx & 7;
            const size_t node = nodeBase + row;
            float tmp[32];
#pragma unroll
            for (int c8 = 0; c8 < 4; ++c8) {
                const int chunk = seg * 4 + c8;
                us8 ov = *(const us8*)(AlB + row * 512 + ((chunk ^ (row & 7)) << 4));
                us8 av = *(const us8*)(aggb + node * 256 + seg * 32 + c8 * 8);
                us8 o;
#pragma unroll
                for (int j = 0; j < 8; ++j) {
                    float val = fmaxf(bf2f(ov[j]) + bf2f(av[j]), 0.f);
                    tmp[c8 * 8 + j] = val;
                    o[j] = f2bf(val);
                }
                *(us8*)(Yb + node * 256 + seg * 32 + c8 * 8) = o;
                if (LAST)
                    *(us8*)(AlB + row * 512 + ((chunk ^ (row & 7)) << 4)) = o;
            }
            if (Yf) {
                float* dst = Yf + node * 256 + seg * 32;
#pragma unroll
                for (int q = 0; q < 8; ++q) {
                    float4 o4; o4.x = tmp[q*4]; o4.y = tmp[q*4+1];
                    o4.z = tmp[q*4+2]; o4.w = tmp[q*4+3];
                    ((float4*)dst)[q] = o4;
                }
            }
        }
    }

    if (LAST) {
        __syncthreads();
        // ---- phase 3: score = y @ lzT + lzb  (K = 256, dbuf) ----
#pragma unroll
        for (int m = 0; m < 4; ++m)
#pragma unroll
            for (int n = 0; n < 4; ++n) oac[m][n] = z4;
        stage2(0, 0, lzT);
        __syncthreads();
        cur = 0;
        for (int ks = 0; ks < 4; ++ks) {
            if (ks < 3) stage2((ks + 1) * 64, cur ^ 1, lzT);
            char* bb = v_buf[cur];
            const int k0 = ks * 64;
#pragma unroll
            for (int kk = 0; kk < 2; ++kk) {
                s16x8 af[4], bf[4];
#pragma unroll
                for (int m = 0; m < 4; ++m) {
                    const int row = wr * 64 + m * 16 + l15;
                    const int chunk = (k0 >> 3) + kk * 4 + lq;
                    af[m] = *(const s16x8*)(AlB + row * 512 + ((chunk ^ (row & 7)) << 4));
                }
#pragma unroll
                for (int n = 0; n < 4; ++n) {
                    const int col = wc * 64 + n * 16 + l15;
                    const int slot = (kk * 4 + lq) ^ (col & 7);
                    bf[n] = *(const s16x8*)(bb + col * 128 + slot * 16);
                }
#pragma unroll
                for (int m = 0; m < 4; ++m)
#pragma unroll
                    for (int n = 0; n < 4; ++n)
                        oac[m][n] = __builtin_amdgcn_mfma_f32_16x16x32_bf16(
                            af[m], bf[n], oac[m][n], 0, 0, 0);
            }
            __syncthreads();
            cur ^= 1;
        }
#pragma unroll
        for (int m = 0; m < 4; ++m)
#pragma unroll
            for (int n = 0; n < 4; ++n) {
                const int col = wc * 64 + n * 16 + l15;
                f32x4 v = oac[m][n];
#pragma unroll
                for (int r = 0; r < 4; ++r) {
                    const int row = wr * 64 + m * 16 + lq * 4 + r;
                    if (row >= SY_) continue;
                    Score[((size_t)z * SY_ + row) * 256 + col] = v[r] + lzb[col];
                }
            }

        // ---- phase 4: Y12 = y @ [gw0|gw1]  (70 x 16, K = 256) ----
        __syncthreads();
        float* Ws = (float*)SBb;
        for (int i = tid; i < 1024; i += 512)
            ((float4*)Ws)[i] = ((const float4*)gw)[i];
        __syncthreads();
        for (int t = tid; t < 1120; t += 512) {
            const int row = t >> 4, j = t & 15;
            const float* Wcol = Ws + ((j < 8) ? j : (2048 + j - 8));
            float a2 = 0.f;
            for (int c = 0; c < 256; ++c) {
                const float yv = bf2f(*(const unsigned short*)(AlB + row * 512 +
                    (((c >> 3) ^ (row & 7)) << 4) + ((c & 7) << 1)));
                a2 = fmaf(yv, Wcol[c * 8], a2);
            }
            Y12g[((size_t)z * SY_ + row) * 16 + j] = a2;
        }
    }
}

// ---------------------------------------------------------------------------
// Merged conversions: x f32->bf16 (blocks 0..2047, grid-stride);
// embeds gather (2048..4287); Wq1/2/3 f32->bf16 into wqcat (4288..4479).
// ---------------------------------------------------------------------------
__global__ __launch_bounds__(256)
void conv_x_embed(const float* __restrict__ in, unsigned short* __restrict__ out,
                  int n8, const float* __restrict__ embeds,
                  const int* __restrict__ tgt_y, unsigned short* __restrict__ yb,
                  const float* __restrict__ wq1, const float* __restrict__ wq2,
                  const float* __restrict__ wq3, unsigned short* __restrict__ wqcat)
{
    if (blockIdx.x < 2048) {
        for (int i = blockIdx.x * 256 + threadIdx.x; i < n8; i += 2048 * 256) {
            float4 a = ((const float4*)in)[i * 2];
            float4 b = ((const float4*)in)[i * 2 + 1];
            us8 o = { f2bf(a.x), f2bf(a.y), f2bf(a.z), f2bf(a.w),
                      f2bf(b.x), f2bf(b.y), f2bf(b.z), f2bf(b.w) };
            ((us8*)out)[i] = o;
        }
    } else if (blockIdx.x < 4288) {
        const int i = (blockIdx.x - 2048) * 8 + (threadIdx.x >> 5);
        const int c8 = (threadIdx.x & 31) * 8;
        const int v = tgt_y[i];
        const float* p = embeds + (size_t)v * 256 + c8;
        float4 a = *(const float4*)p;
        float4 b = *(const float4*)(p + 4);
        us8 o = { f2bf(a.x), f2bf(a.y), f2bf(a.z), f2bf(a.w),
                  f2bf(b.x), f2bf(b.y), f2bf(b.z), f2bf(b.w) };
        *(us8*)(yb + (size_t)i * 256 + c8) = o;
    } else {
        const int idx = blockIdx.x - 4288;           // 0..191
        const int which = idx >> 6;                  // 0,1,2
        const int i = (idx & 63) * 256 + threadIdx.x; // us8 index < 16384
        const float* src = (which == 0) ? wq1 : (which == 1) ? wq2 : wq3;
        float4 a = ((const float4*)src)[i * 2];
        float4 b = ((const float4*)src)[i * 2 + 1];
        us8 o = { f2bf(a.x), f2bf(a.y), f2bf(a.z), f2bf(a.w),
                  f2bf(b.x), f2bf(b.y), f2bf(b.z), f2bf(b.w) };
        ((us8*)(wqcat + (size_t)which * 131072))[i] = o;
    }
}

// ---------------------------------------------------------------------------
// Weight transposes in ONE dispatch. Grid (8, 8, 8); out-of-range exit.
// Slots: 0-2 W_in (256x256), 3-5 Wv (512x256), 6 lin_z (256x256).
// ---------------------------------------------------------------------------
struct WAll {
    const float* src[8];
    unsigned short* dst[8];
    int R[8];
    int C[8];
};

__global__ __launch_bounds__(256)
void conv_wT_all(WAll d)
{
    const int z = blockIdx.z;
    if (z >= 7) return;
    const int R = d.R[z], C = d.C[z];
    const int c0 = blockIdx.x * 64, r0 = blockIdx.y * 64;
    if (c0 >= C || r0 >= R) return;
    const float* in = d.src[z];
    unsigned short* outT = d.dst[z];
    __shared__ unsigned short t[64][65];
    const int r = threadIdx.x >> 4, cq = (threadIdx.x & 15) << 2;
#pragma unroll
    for (int i = 0; i < 4; ++i) {
        const int rr = r + i * 16;
        float4 v = *(const float4*)(in + (size_t)(r0 + rr) * C + c0 + cq);
        t[rr][cq + 0] = f2bf(v.x); t[rr][cq + 1] = f2bf(v.y);
        t[rr][cq + 2] = f2bf(v.z); t[rr][cq + 3] = f2bf(v.w);
    }
    __syncthreads();
    const int c = threadIdx.x >> 2, sq = (threadIdx.x & 3) << 4;
    us8 o0, o1;
#pragma unroll
    for (int i = 0; i < 8; ++i) { o0[i] = t[sq + i][c]; o1[i] = t[sq + 8 + i][c]; }
    *(us8*)(outT + (size_t)(c0 + c) * R + r0 + sq) = o0;
    *(us8*)(outT + (size_t)(c0 + c) * R + r0 + sq + 8) = o1;
}

// ---------------------------------------------------------------------------
// CSR build (4 small parallel dispatches — proven fast)
// ---------------------------------------------------------------------------
__global__ __launch_bounds__(256)
void edge_deg(const int* __restrict__ tgt, int* __restrict__ deg)
{
    const int e = blockIdx.x * 256 + threadIdx.x;
    if (e < NE_) atomicAdd(&deg[tgt[e]], 1);
}

__global__ __launch_bounds__(1024)
void scan_off(const int* __restrict__ deg, int* __restrict__ off, int* __restrict__ cursor)
{
    __shared__ int ls[1024];
    const int t = threadIdx.x;
    const int base = t * 18;
    int local[18];
    int s = 0;
#pragma unroll
    for (int i = 0; i < 18; ++i) {
        const int idx = base + i;
        const int v = (idx < NY_) ? deg[idx] : 0;
        local[i] = s; s += v;
    }
    ls[t] = s;
    __syncthreads();
    for (int d = 1; d < 1024; d <<= 1) {
        int v = (t >= d) ? ls[t - d] : 0;
        __syncthreads();
        ls[t] += v;
        __syncthreads();
    }
    const int excl = (t == 0) ? 0 : ls[t - 1];
#pragma unroll
    for (int i = 0; i < 18; ++i) {
        const int idx = base + i;
        if (idx < NY_) {
            const int o = excl + local[i];
            off[idx] = o; cursor[idx] = o;
        }
    }
    if (t == 1023) off[NY_] = ls[1023];
}

__global__ __launch_bounds__(256)
void edge_fill(const int* __restrict__ tgt, int* __restrict__ cursor,
               int* __restrict__ elist)
{
    const int e = blockIdx.x * 256 + threadIdx.x;
    if (e >= NE_) return;
    const int pos = atomicAdd(&cursor[tgt[e]], 1);
    elist[pos] = e;
}

// ---------------------------------------------------------------------------
// aggb[t,:] = bf16( hb[t,:] + sum_{e in bucket(t)} hb[src[e],:] + cnt * Ee )
// ---------------------------------------------------------------------------
__global__ __launch_bounds__(256)
void node_agg(const unsigned short* __restrict__ hb,
              const float* __restrict__ Ee,
              const int* __restrict__ src, const int* __restrict__ etype,
              const int* __restrict__ off, const int* __restrict__ elist,
              unsigned short* __restrict__ aggb)
{
    const int nid  = blockIdx.x * 4 + (threadIdx.x >> 6);
    const int lane = threadIdx.x & 63;
    const int c = lane * 4;
    const int k0 = off[nid], k1 = off[nid + 1];
    us4 sv = *(const us4*)(hb + (size_t)nid * 256 + c);
    float4 acc;
    acc.x = bf2f(sv[0]); acc.y = bf2f(sv[1]);
    acc.z = bf2f(sv[2]); acc.w = bf2f(sv[3]);
    int cnt0 = 0, cnt1 = 0, cnt2 = 0, cnt3 = 0;
    for (int k = k0; k < k1; ++k) {
        const int e = elist[k];
        const int sfrom = src[e];
        const int ty = etype[e];
        us4 hv = *(const us4*)(hb + (size_t)sfrom * 256 + c);
        acc.x += bf2f(hv[0]); acc.y += bf2f(hv[1]);
        acc.z += bf2f(hv[2]); acc.w += bf2f(hv[3]);
        cnt0 += (ty == 0); cnt1 += (ty == 1); cnt2 += (ty == 2); cnt3 += (ty == 3);
    }
    float4 e0 = *(const float4*)(Ee + c);
    float4 e1 = *(const float4*)(Ee + 256 + c);
    float4 e2 = *(const float4*)(Ee + 512 + c);
    float4 e3 = *(const float4*)(Ee + 768 + c);
    acc.x += cnt0 * e0.x + cnt1 * e1.x + cnt2 * e2.x + cnt3 * e3.x;
    acc.y += cnt0 * e0.y + cnt1 * e1.y + cnt2 * e2.y + cnt3 * e3.y;
    acc.z += cnt0 * e0.z + cnt1 * e1.z + cnt2 * e2.z + cnt3 * e3.z;
    acc.w += cnt0 * e0.w + cnt1 * e1.w + cnt2 * e2.w + cnt3 * e3.w;
    us4 o = { f2bf(acc.x), f2bf(acc.y), f2bf(acc.z), f2bf(acc.w) };
    *(us4*)(aggb + (size_t)nid * 256 + c) = o;
}

// ---------------------------------------------------------------------------
// esc[e,0:8] = Y12[src[e],0:8] + Y12[tgt[e],8:16] + b
// ---------------------------------------------------------------------------
__global__ __launch_bounds__(256)
void edge_gather(const float* __restrict__ Y12, const int* __restrict__ src,
                 const int* __restrict__ tgt, const float* __restrict__ bias,
                 float* __restrict__ esc)
{
    const int e = blockIdx.x * 256 + threadIdx.x;
    if (e >= NE_) return;
    const float* a = Y12 + (size_t)src[e] * 16;
    const float* b = Y12 + (size_t)tgt[e] * 16 + 8;
    float4 a0 = ((const float4*)a)[0], a1 = ((const float4*)a)[1];
    float4 b0 = ((const float4*)b)[0], b1 = ((const float4*)b)[1];
    float4 c0 = ((const float4*)bias)[0], c1 = ((const float4*)bias)[1];
    float4 o0, o1;
    o0.x = a0.x + b0.x + c0.x; o0.y = a0.y + b0.y + c0.y;
    o0.z = a0.z + b0.z + c0.z; o0.w = a0.w + b0.w + c0.w;
    o1.x = a1.x + b1.x + c1.x; o1.y = a1.y + b1.y + c1.y;
    o1.z = a1.z + b1.z + c1.z; o1.w = a1.w + b1.w + c1.w;
    ((float4*)(esc + (size_t)e * 8))[0] = o0;
    ((float4*)(esc + (size_t)e * 8))[1] = o1;
}

// ---------------------------------------------------------------------------
extern "C" void kernel_launch(void* const* d_in, const int* in_sizes, int n_in,
                              void* d_out, int out_size, void* d_ws, size_t ws_size,
                              hipStream_t stream)
{
    const float* x       = (const float*)d_in[0];
    const int*   tgt_y   = (const int*)d_in[2];
    const int*   eidx    = (const int*)d_in[3];
    const int*   etype   = (const int*)d_in[4];
    const float* embeds  = (const float*)d_in[6];
    const float* W_in[3] = {(const float*)d_in[7],  (const float*)d_in[11], (const float*)d_in[15]};
    const float* Wq[3]   = {(const float*)d_in[8],  (const float*)d_in[12], (const float*)d_in[16]};
    const float* Wv[3]   = {(const float*)d_in[9],  (const float*)d_in[13], (const float*)d_in[17]};
    const float* Ee[3]   = {(const float*)d_in[10], (const float*)d_in[14], (const float*)d_in[18]};
    const float* lin_z_w = (const float*)d_in[19];
    const float* lin_z_b = (const float*)d_in[20];
    const float* lin_g_w = (const float*)d_in[21];
    const float* lin_g_b = (const float*)d_in[22];
    const int* src = eidx;
    const int* tgt = eidx + NE_;

    float* out = (float*)d_out;
    // d_out layout (floats)
    float* y_final = out;                        // [17920][256]
    float* score   = out + 4587520;              // [17920][256]
    float* esc     = out + 9175040;              // [71680][8]
    float* aout[3] = {out + 9748480, out + 14336000, out + 18923520}; // [B][70][256]

    // workspace layout (bytes)
    char* wsb = (char*)d_ws;
    unsigned short* xb     = (unsigned short*)(wsb + 0);            //  67,108,864
    unsigned short* xvTall = (unsigned short*)(wsb + 67108864);     // 100,663,296  [B][768][256]
    unsigned short* xqTall = (unsigned short*)(wsb + 167772160);    // 100,663,296  [B][256][768]
    unsigned short* hb     = (unsigned short*)(wsb + 268435456);    //   9,175,040
    unsigned short* aggb   = (unsigned short*)(wsb + 277610496);    //   9,175,040
    unsigned short* yb     = (unsigned short*)(wsb + 286785536);    //   9,175,040
    char* wt = wsb + 295960576;                                     //   2,097,152
    unsigned short* winT[3], *wqT[3], *wvT[3];
    for (int l = 0; l < 3; ++l) {
        winT[l] = (unsigned short*)(wt + l * 131072);                 // [256][256]
        wqT[l]  = (unsigned short*)(wt + 393216  + l * 262144);       // wqcat [768][512]
        wvT[l]  = (unsigned short*)(wt + 1179648 + l * 262144);       // wvcat [768][512]
    }
    unsigned short* lzT = (unsigned short*)(wt + 1966080);
    char* extra = wsb + 298057728;
    float* Y12    = (float*)extra;                 // 1,146,880
    int*   deg    = (int*)(extra + 1146880);       //    71,680
    int*   off    = (int*)(extra + 1218560);       //    71,684
    int*   cursor = (int*)(extra + 1290244);       //    71,680
    int*   elist  = (int*)(extra + 1361924);       //   286,720  (end ~299.7 MB)

    // --- CSR build (parallel 4-dispatch pipeline) ---
    hipMemsetAsync(deg, 0, NY_ * sizeof(int), stream);
    edge_deg<<<280, 256, 0, stream>>>(tgt, deg);
    scan_off<<<1, 1024, 0, stream>>>(deg, off, cursor);
    edge_fill<<<280, 256, 0, stream>>>(tgt, cursor, elist);

    // --- one-time conversions: x, embeds, Wq (straight bf16) ---
    conv_x_embed<<<4480, 256, 0, stream>>>(x, xb, 4194304, embeds, tgt_y, yb,
                                           Wq[0], Wq[1], Wq[2], wqT[0]);
    WAll wd;
    for (int l = 0; l < 3; ++l) {
        wd.src[l]     = W_in[l]; wd.dst[l]     = winT[l]; wd.R[l]     = 256; wd.C[l]     = 256;
        wd.src[3 + l] = Wv[l];   wd.dst[3 + l] = wvT[l];  wd.R[3 + l] = 512; wd.C[3 + l] = 256;
    }
    wd.src[6] = lin_z_w; wd.dst[6] = lzT; wd.R[6] = 256; wd.C[6] = 256;
    wd.src[7] = lin_z_w; wd.dst[7] = lzT; wd.R[7] = 0; wd.C[7] = 0;
    conv_wT_all<<<dim3(8, 8, 7), 256, 0, stream>>>(wd);

    // --- xvTall[b] = [Wv1;Wv2;Wv3]^T-concat @ x_b^T : [768][256] per batch ---
    gemm_mfma<1><<<3072, 256, 0, stream>>>(
        wvT[0], 512, 0,  xb, 512, (long)SX_ * F_,
        nullptr, 0, 0,  xvTall, 256, 768L * 256,
        768, 512, 1.f, 2, 6);

    // --- xqTall[b] = x_b @ [Wq1;Wq2;Wq3]^T : [256 rows][768] per batch ---
    gemm_mfma<1><<<3072, 256, 0, stream>>>(
        xb, 512, (long)SX_ * F_,  wqT[0], 512, 0,
        nullptr, 0, 0,  xqTall, 768, 256L * 768,
        256, 512, 1.f, 6, 2);

    const float qscale = 0.044194173824159216f;  // 1/sqrt(512)
    for (int l = 0; l < 3; ++l) {
        // hb = bf16(y @ W_in)
        gemm_mfma<0><<<dim3(2, 140, 1), 256, 0, stream>>>(
            yb, 256, 0,  winT[l], 256, 0,
            nullptr, 0, 0,  hb, 256, 0,
            NY_, 256, 1.f, 0, 0);
        // aggb = bf16(h + segment_sum(h[src] + Ee[etype], tgt))
        node_agg<<<4480, 256, 0, stream>>>(hb, Ee[l], src, etype, off, elist, aggb);
        // fused attn: S = hb @ xqT^T; softmax; PV + relu (+ score, Y12 on last)
        if (l < 2) {
            attn_pv<0><<<256, 512, 0, stream>>>(
                hb, xqTall + (size_t)l * 256, xvTall + (size_t)l * 65536, 768L * 256,
                aggb, nullptr, nullptr, nullptr, nullptr,
                aout[l], yb, nullptr, nullptr, qscale);
        } else {
            attn_pv<1><<<256, 512, 0, stream>>>(
                hb, xqTall + (size_t)l * 256, xvTall + (size_t)l * 65536, 768L * 256,
                aggb, lzT, lin_z_b, lin_g_w, Y12,
                aout[l], yb, y_final, score, qscale);
        }
    }
    // edge relation scores from Y12
    edge_gather<<<280, 256, 0, stream>>>(Y12, src, tgt, lin_g_b, esc);
}

// Round 25
// 436.122 us; speedup vs baseline: 1.0230x; 1.0230x over previous
//
#include <hip/hip_runtime.h>
#include <cstddef>
#include <cstdint>

#define B_    256
#define SX_   256
#define SY_   70
#define F_    512
#define EMB_  256
#define NY_   (B_*SY_)     // 17920
#define NE_   (4*B_*SY_)   // 71680

typedef short s16x8 __attribute__((ext_vector_type(8)));   // MFMA A/B frag (8 bf16)
typedef float f32x4 __attribute__((ext_vector_type(4)));   // MFMA C/D frag
typedef unsigned short us4 __attribute__((ext_vector_type(4)));
typedef unsigned short us8 __attribute__((ext_vector_type(8)));

__device__ __forceinline__ unsigned short f2bf(float f) {
    unsigned u = __builtin_bit_cast(unsigned, f);
    u += 0x7fffu + ((u >> 16) & 1u);          // RNE
    return (unsigned short)(u >> 16);
}
__device__ __forceinline__ float bf2f(unsigned short b) {
    unsigned u = ((unsigned)b) << 16;
    return __builtin_bit_cast(float, u);
}

// ---------------------------------------------------------------------------
// Unified bf16 MFMA GEMM, C = A @ Bt^T. A:[M][K] bf16, Bt:[N][K] bf16.
// 128x128 tile, BK=64, 4 waves (2x2 of 64x64), 16x16x32 MFMA.
// EPI: 0 = plain; 7 = dual-bf16 split: col<256 -> Cb (ld 256),
//      col>=256 -> (ushort*)Cf (ld 512).
// SWZ: 1 = flattened 1D grid with bijective XCD remap (gridDim.x % 8 == 0).
// ---------------------------------------------------------------------------
template<int EPI, int SWZ>
__global__ __launch_bounds__(256, 2)
void gemm_mfma(const unsigned short* __restrict__ A, int lda, long sAb,
               const unsigned short* __restrict__ Bt, int ldb, long sBb,
               float* __restrict__ Cf, int ldc, long sCfb,
               unsigned short* __restrict__ Cb, int ldcb, long sCbb,
               int M, int K, float scale, int nx, int ny)
{
    __shared__ unsigned short As[128 * 64];
    __shared__ unsigned short Bs[128 * 64];
    char* AsB = (char*)As;
    char* BsB = (char*)Bs;
    const int tid = threadIdx.x;
    int bxi, byi, z;
    if (SWZ) {
        const int nwg = gridDim.x;
        const int bid = blockIdx.x;
        const int wg = (bid & 7) * (nwg >> 3) + (bid >> 3);
        bxi = wg % nx;
        byi = (wg / nx) % ny;
        z   = wg / (nx * ny);
    } else {
        bxi = blockIdx.x; byi = blockIdx.y; z = blockIdx.z;
    }
    A  += (size_t)z * sAb;
    Bt += (size_t)z * sBb;
    const int bm = byi * 128, bn = bxi * 128;
    const int lane = tid & 63;
    const int w = tid >> 6, wr = w >> 1, wc = w & 1;
    const int l15 = lane & 15, lq = lane >> 4;

    f32x4 acc[4][4];
    const f32x4 z4 = {0.f, 0.f, 0.f, 0.f};
#pragma unroll
    for (int m = 0; m < 4; ++m)
#pragma unroll
        for (int n = 0; n < 4; ++n) acc[m][n] = z4;

    for (int k0 = 0; k0 < K; k0 += 64) {
#pragma unroll
        for (int i = 0; i < 4; ++i) {
            const int row = i * 32 + (tid >> 3);
            const int k8  = (tid & 7) ^ (row & 7);
            int ra = bm + row; ra = (ra < M) ? ra : (M - 1);
            const unsigned short* g = A + (size_t)ra * lda + k0 + k8 * 8;
            __builtin_amdgcn_global_load_lds(
                (const __attribute__((address_space(1))) unsigned int*)g,
                (__attribute__((address_space(3))) unsigned int*)(AsB + i * 4096 + tid * 16),
                16, 0, 0);
        }
#pragma unroll
        for (int i = 0; i < 4; ++i) {
            const int row = i * 32 + (tid >> 3);
            const int k8  = (tid & 7) ^ (row & 7);
            const unsigned short* g = Bt + (size_t)(bn + row) * ldb + k0 + k8 * 8;
            __builtin_amdgcn_global_load_lds(
                (const __attribute__((address_space(1))) unsigned int*)g,
                (__attribute__((address_space(3))) unsigned int*)(BsB + i * 4096 + tid * 16),
                16, 0, 0);
        }
        __syncthreads();
#pragma unroll
        for (int kk = 0; kk < 2; ++kk) {
            s16x8 af[4], bf[4];
#pragma unroll
            for (int m = 0; m < 4; ++m) {
                const int row = wr * 64 + m * 16 + l15;
                const int slot = (kk * 4 + lq) ^ (row & 7);
                af[m] = *(const s16x8*)(AsB + row * 128 + slot * 16);
            }
#pragma unroll
            for (int n = 0; n < 4; ++n) {
                const int col = wc * 64 + n * 16 + l15;
                const int slot = (kk * 4 + lq) ^ (col & 7);
                bf[n] = *(const s16x8*)(BsB + col * 128 + slot * 16);
            }
#pragma unroll
            for (int m = 0; m < 4; ++m)
#pragma unroll
                for (int n = 0; n < 4; ++n)
                    acc[m][n] = __builtin_amdgcn_mfma_f32_16x16x32_bf16(
                        af[m], bf[n], acc[m][n], 0, 0, 0);
        }
        __syncthreads();
    }

    float* cf = Cf ? Cf + (size_t)z * sCfb : nullptr;
    unsigned short* cb = Cb ? Cb + (size_t)z * sCbb : nullptr;
#pragma unroll
    for (int m = 0; m < 4; ++m) {
#pragma unroll
        for (int n = 0; n < 4; ++n) {
            const int col = bn + wc * 64 + n * 16 + l15;
            f32x4 v = acc[m][n];
#pragma unroll
            for (int r = 0; r < 4; ++r) {
                const int gr = bm + wr * 64 + m * 16 + lq * 4 + r;
                if (gr >= M) continue;
                float o = v[r] * scale;
                if (EPI == 7) {
                    if (col < 256) cb[(size_t)gr * ldcb + col] = f2bf(o);
                    else ((unsigned short*)cf)[(size_t)gr * 512 + (col - 256)] = f2bf(o);
                } else {
                    if (cf) cf[(size_t)gr * ldc + col] = o;
                    if (cb) cb[(size_t)gr * ldcb + col] = f2bf(o);
                }
            }
        }
    }
}

// ---------------------------------------------------------------------------
// Fused attention layer kernel. Grid 512: block b handles batch b>>1,
// rows [h0, h0+35) with h0 = (b&1)*35, padded to 64. 4 waves, 256 threads,
// 73 KB LDS -> 2 blocks/CU (co-resident blocks hide barrier stalls).
// Phase 1: S = scale * Q @ X^T (K=512, BK=32, dbuf).
// Middle: softmax; alpha bf16 -> Al (swizzled); vectorized alpha dump.
// Phase 2: O = alpha @ xv (K=256, single buf); vectorized y dump.
// Phase 3 (LAST): score = y @ lzT + lzb.  Phase 4 (LAST): Y12 = y @ gw.
// ---------------------------------------------------------------------------
template<int LAST>
__global__ __launch_bounds__(256, 2)
void attn_pv(const unsigned short* __restrict__ Q,    // [B][70][512]
             const unsigned short* __restrict__ X,    // [B][256][512]
             const unsigned short* __restrict__ XV,   // [B][768][256] slice
             long sXVb,
             const unsigned short* __restrict__ aggb, // [17920][256] bf16
             const unsigned short* __restrict__ lzT,  // [256][256] bf16 (LAST)
             const float* __restrict__ lzb,           // [256] f32 (LAST)
             const float* __restrict__ gw,            // [512][8] f32 (LAST)
             float* __restrict__ Y12g,                // [17920][16] f32 (LAST)
             float* __restrict__ Aout,                // [B][70][256]
             unsigned short* __restrict__ Yb,         // [17920][256] bf16
             float* __restrict__ Yf,                  // f32 or null
             float* __restrict__ Score,               // [17920][256] f32 (LAST)
             float scale)
{
    __shared__ unsigned short SB[2 * 10240];  // 40 KB: ph1 2x20KB; ph2/3 32KB
    __shared__ unsigned short Al[64 * 256];   // 32 KB (alpha / O / y, swizzled)
    __shared__ float red[4][64];              // 1 KB
    char* SBb = (char*)SB;
    char* AlB = (char*)Al;
    const int tid = threadIdx.x;
    const int z  = blockIdx.x >> 1;
    const int h0 = (blockIdx.x & 1) * 35;
    const unsigned short* Qb  = Q + (size_t)z * SY_ * F_;
    const unsigned short* Xb  = X + (size_t)z * SX_ * F_;
    const unsigned short* xvb = XV + (size_t)z * sXVb;
    const int lane = tid & 63;
    const int wc = tid >> 6;                  // 4 waves = 4 col strips
    const int l15 = lane & 15, lq = lane >> 4;

    // ---- phase 1: S = Q @ X^T  (K=512, BK=32, 16 steps, dbuf) ----
    // buf = 20KB { A 64x32 @0 (4KB, 64B rows, slot swz lq^((row>>1)&3)),
    //              B 256x32 @4096 (16KB) }
    auto stage1 = [&](int t, int buf) {
        char* base = SBb + buf * 20480;
        {
            const int row = tid >> 2;
            const int k8  = (tid & 3) ^ ((row >> 1) & 3);
            const int rl  = (row < 35) ? row : 34;
            const unsigned short* g = Qb + (size_t)(h0 + rl) * F_ + t * 32 + k8 * 8;
            __builtin_amdgcn_global_load_lds(
                (const __attribute__((address_space(1))) unsigned int*)g,
                (__attribute__((address_space(3))) unsigned int*)(base + tid * 16),
                16, 0, 0);
        }
#pragma unroll
        for (int i = 0; i < 4; ++i) {
            const int row = i * 64 + (tid >> 2);
            const int k8  = (tid & 3) ^ ((row >> 1) & 3);
            const unsigned short* g = Xb + (size_t)row * F_ + t * 32 + k8 * 8;
            __builtin_amdgcn_global_load_lds(
                (const __attribute__((address_space(1))) unsigned int*)g,
                (__attribute__((address_space(3))) unsigned int*)(base + 4096 + i * 4096 + tid * 16),
                16, 0, 0);
        }
    };

    f32x4 acc[4][4];
    const f32x4 z4 = {0.f, 0.f, 0.f, 0.f};
#pragma unroll
    for (int m = 0; m < 4; ++m)
#pragma unroll
        for (int n = 0; n < 4; ++n) acc[m][n] = z4;

    stage1(0, 0);
    __syncthreads();
    int cur = 0;
    for (int t = 0; t < 16; ++t) {
        if (t < 15) stage1(t + 1, cur ^ 1);
        char* base = SBb + cur * 20480;
        s16x8 af[4], bf[4];
#pragma unroll
        for (int m = 0; m < 4; ++m) {
            const int row = m * 16 + l15;
            const int slot = lq ^ ((row >> 1) & 3);
            af[m] = *(const s16x8*)(base + row * 64 + slot * 16);
        }
#pragma unroll
        for (int n = 0; n < 4; ++n) {
            const int col = wc * 64 + n * 16 + l15;
            const int slot = lq ^ ((col >> 1) & 3);
            bf[n] = *(const s16x8*)(base + 4096 + col * 64 + slot * 16);
        }
#pragma unroll
        for (int m = 0; m < 4; ++m)
#pragma unroll
            for (int n = 0; n < 4; ++n)
                acc[m][n] = __builtin_amdgcn_mfma_f32_16x16x32_bf16(
                    af[m], bf[n], acc[m][n], 0, 0, 0);
        __syncthreads();
        cur ^= 1;
    }

    // ---- softmax (rows 0..63 local; each wave has 64-col partials) ----
#pragma unroll
    for (int m = 0; m < 4; ++m)
#pragma unroll
        for (int n = 0; n < 4; ++n)
#pragma unroll
            for (int r = 0; r < 4; ++r) acc[m][n][r] *= scale;

    float rmax[4][4];
#pragma unroll
    for (int m = 0; m < 4; ++m)
#pragma unroll
        for (int r = 0; r < 4; ++r) {
            float mx = acc[m][0][r];
#pragma unroll
            for (int n = 1; n < 4; ++n) mx = fmaxf(mx, acc[m][n][r]);
            mx = fmaxf(mx, __shfl_xor(mx, 1));
            mx = fmaxf(mx, __shfl_xor(mx, 2));
            mx = fmaxf(mx, __shfl_xor(mx, 4));
            mx = fmaxf(mx, __shfl_xor(mx, 8));
            rmax[m][r] = mx;
        }
    if (l15 == 0) {
#pragma unroll
        for (int m = 0; m < 4; ++m)
#pragma unroll
            for (int r = 0; r < 4; ++r)
                red[wc][m * 16 + lq * 4 + r] = rmax[m][r];
    }
    __syncthreads();
    float rtot[4][4];
#pragma unroll
    for (int m = 0; m < 4; ++m)
#pragma unroll
        for (int r = 0; r < 4; ++r) {
            const int lr = m * 16 + lq * 4 + r;
            rtot[m][r] = fmaxf(fmaxf(red[0][lr], red[1][lr]),
                               fmaxf(red[2][lr], red[3][lr]));
        }
    __syncthreads();
    float rsum[4][4];
#pragma unroll
    for (int m = 0; m < 4; ++m)
#pragma unroll
        for (int r = 0; r < 4; ++r) {
            float s = 0.f;
#pragma unroll
            for (int n = 0; n < 4; ++n) {
                float e = __expf(acc[m][n][r] - rtot[m][r]);
                acc[m][n][r] = e;
                s += e;
            }
            s += __shfl_xor(s, 1);
            s += __shfl_xor(s, 2);
            s += __shfl_xor(s, 4);
            s += __shfl_xor(s, 8);
            rsum[m][r] = s;
        }
    if (l15 == 0) {
#pragma unroll
        for (int m = 0; m < 4; ++m)
#pragma unroll
            for (int r = 0; r < 4; ++r)
                red[wc][m * 16 + lq * 4 + r] = rsum[m][r];
    }
    __syncthreads();
    // ---- alpha: bf16 -> LDS Al (swizzled, 64 rows x 256 cols) ----
#pragma unroll
    for (int m = 0; m < 4; ++m)
#pragma unroll
        for (int r = 0; r < 4; ++r) {
            const int lr = m * 16 + lq * 4 + r;
            const float inv = 1.0f / (red[0][lr] + red[1][lr] +
                                      red[2][lr] + red[3][lr]);
#pragma unroll
            for (int n = 0; n < 4; ++n) {
                const int col = wc * 64 + n * 16 + l15;
                *(unsigned short*)(AlB + lr * 512 +
                    (((col >> 3) ^ (lr & 7)) << 4) + ((col & 7) << 1))
                    = f2bf(acc[m][n][r] * inv);
            }
        }
    __syncthreads();
    // ---- vectorized alpha dump: Al bf16 -> Aout f32 (local rows < 35) ----
    {
        float* ao = Aout + (size_t)z * SY_ * SX_ + (size_t)h0 * SX_;
        for (int idx = tid; idx < 35 * 8; idx += 256) {
            const int row = idx >> 3, seg = idx & 7;
            float tmp[32];
#pragma unroll
            for (int c8 = 0; c8 < 4; ++c8) {
                const int chunk = seg * 4 + c8;
                us8 v = *(const us8*)(AlB + row * 512 + ((chunk ^ (row & 7)) << 4));
#pragma unroll
                for (int j = 0; j < 8; ++j) tmp[c8 * 8 + j] = bf2f(v[j]);
            }
            float* dst = ao + (size_t)row * SX_ + seg * 32;
#pragma unroll
            for (int q = 0; q < 8; ++q) {
                float4 o4; o4.x = tmp[q*4]; o4.y = tmp[q*4+1];
                o4.z = tmp[q*4+2]; o4.w = tmp[q*4+3];
                ((float4*)dst)[q] = o4;
            }
        }
    }

    // ---- phase 2: O = alpha @ xv (K=256, single 32KB buffer) ----
    auto stage2 = [&](int k0, const unsigned short* srcm) {
#pragma unroll
        for (int i = 0; i < 8; ++i) {
            const int row = i * 32 + (tid >> 3);
            const int k8  = (tid & 7) ^ (row & 7);
            const unsigned short* g = srcm + (size_t)row * 256 + k0 + k8 * 8;
            __builtin_amdgcn_global_load_lds(
                (const __attribute__((address_space(1))) unsigned int*)g,
                (__attribute__((address_space(3))) unsigned int*)(SBb + i * 4096 + tid * 16),
                16, 0, 0);
        }
    };

    f32x4 oac[4][4];
#pragma unroll
    for (int m = 0; m < 4; ++m)
#pragma unroll
        for (int n = 0; n < 4; ++n) oac[m][n] = z4;

    for (int ks = 0; ks < 4; ++ks) {
        stage2(ks * 64, xvb);
        __syncthreads();
        const int k0 = ks * 64;
#pragma unroll
        for (int kk = 0; kk < 2; ++kk) {
            s16x8 af[4], bf[4];
#pragma unroll
            for (int m = 0; m < 4; ++m) {
                const int row = m * 16 + l15;
                const int chunk = (k0 >> 3) + kk * 4 + lq;
                af[m] = *(const s16x8*)(AlB + row * 512 + ((chunk ^ (row & 7)) << 4));
            }
#pragma unroll
            for (int n = 0; n < 4; ++n) {
                const int col = wc * 64 + n * 16 + l15;
                const int slot = (kk * 4 + lq) ^ (col & 7);
                bf[n] = *(const s16x8*)(SBb + col * 128 + slot * 16);
            }
#pragma unroll
            for (int m = 0; m < 4; ++m)
#pragma unroll
                for (int n = 0; n < 4; ++n)
                    oac[m][n] = __builtin_amdgcn_mfma_f32_16x16x32_bf16(
                        af[m], bf[n], oac[m][n], 0, 0, 0);
        }
        __syncthreads();
    }

    // ---- O bf16 -> Al (local rows < 35) ----
#pragma unroll
    for (int m = 0; m < 4; ++m)
#pragma unroll
        for (int n = 0; n < 4; ++n) {
            const int col = wc * 64 + n * 16 + l15;
            f32x4 v = oac[m][n];
#pragma unroll
            for (int r = 0; r < 4; ++r) {
                const int row = m * 16 + lq * 4 + r;
                if (row >= 35) continue;
                *(unsigned short*)(AlB + row * 512 +
                    (((col >> 3) ^ (row & 7)) << 4) + ((col & 7) << 1)) = f2bf(v[r]);
            }
        }
    __syncthreads();
    // ---- vectorized y dump: y = relu(O + aggb) -> Yb (+Yf), y -> Al ----
    {
        const size_t nodeBase = (size_t)z * SY_ + h0;
        for (int idx = tid; idx < 35 * 8; idx += 256) {
            const int row = idx >> 3, seg = idx & 7;
            const size_t node = nodeBase + row;
            float tmp[32];
#pragma unroll
            for (int c8 = 0; c8 < 4; ++c8) {
                const int chunk = seg * 4 + c8;
                us8 ov = *(const us8*)(AlB + row * 512 + ((chunk ^ (row & 7)) << 4));
                us8 av = *(const us8*)(aggb + node * 256 + seg * 32 + c8 * 8);
                us8 o;
#pragma unroll
                for (int j = 0; j < 8; ++j) {
                    float val = fmaxf(bf2f(ov[j]) + bf2f(av[j]), 0.f);
                    tmp[c8 * 8 + j] = val;
                    o[j] = f2bf(val);
                }
                *(us8*)(Yb + node * 256 + seg * 32 + c8 * 8) = o;
                if (LAST)
                    *(us8*)(AlB + row * 512 + ((chunk ^ (row & 7)) << 4)) = o;
            }
            if (Yf) {
                float* dst = Yf + node * 256 + seg * 32;
#pragma unroll
                for (int q = 0; q < 8; ++q) {
                    float4 o4; o4.x = tmp[q*4]; o4.y = tmp[q*4+1];
                    o4.z = tmp[q*4+2]; o4.w = tmp[q*4+3];
                    ((float4*)dst)[q] = o4;
                }
            }
        }
    }

    if (LAST) {
        __syncthreads();
        // ---- phase 3: score = y @ lzT + lzb  (K = 256) ----
#pragma unroll
        for (int m = 0; m < 4; ++m)
#pragma unroll
            for (int n = 0; n < 4; ++n) oac[m][n] = z4;
        for (int ks = 0; ks < 4; ++ks) {
            stage2(ks * 64, lzT);
            __syncthreads();
            const int k0 = ks * 64;
#pragma unroll
            for (int kk = 0; kk < 2; ++kk) {
                s16x8 af[4], bf[4];
#pragma unroll
                for (int m = 0; m < 4; ++m) {
                    const int row = m * 16 + l15;
                    const int chunk = (k0 >> 3) + kk * 4 + lq;
                    af[m] = *(const s16x8*)(AlB + row * 512 + ((chunk ^ (row & 7)) << 4));
                }
#pragma unroll
                for (int n = 0; n < 4; ++n) {
                    const int col = wc * 64 + n * 16 + l15;
                    const int slot = (kk * 4 + lq) ^ (col & 7);
                    bf[n] = *(const s16x8*)(SBb + col * 128 + slot * 16);
                }
#pragma unroll
                for (int m = 0; m < 4; ++m)
#pragma unroll
                    for (int n = 0; n < 4; ++n)
                        oac[m][n] = __builtin_amdgcn_mfma_f32_16x16x32_bf16(
                            af[m], bf[n], oac[m][n], 0, 0, 0);
            }
            __syncthreads();
        }
#pragma unroll
        for (int m = 0; m < 4; ++m)
#pragma unroll
            for (int n = 0; n < 4; ++n) {
                const int col = wc * 64 + n * 16 + l15;
                f32x4 v = oac[m][n];
#pragma unroll
                for (int r = 0; r < 4; ++r) {
                    const int row = m * 16 + lq * 4 + r;
                    if (row >= 35) continue;
                    Score[((size_t)z * SY_ + h0 + row) * 256 + col] = v[r] + lzb[col];
                }
            }

        // ---- phase 4: Y12 = y @ [gw0|gw1]  (35 x 16, K = 256) ----
        __syncthreads();
        float* Ws = (float*)SBb;
        for (int i = tid; i < 1024; i += 256)
            ((float4*)Ws)[i] = ((const float4*)gw)[i];
        __syncthreads();
        for (int t = tid; t < 35 * 16; t += 256) {
            const int row = t >> 4, j = t & 15;
            const float* Wcol = Ws + ((j < 8) ? j : (2048 + j - 8));
            float a2 = 0.f;
            for (int c = 0; c < 256; ++c) {
                const float yv = bf2f(*(const unsigned short*)(AlB + row * 512 +
                    (((c >> 3) ^ (row & 7)) << 4) + ((c & 7) << 1)));
                a2 = fmaf(yv, Wcol[c * 8], a2);
            }
            Y12g[((size_t)z * SY_ + h0 + row) * 16 + j] = a2;
        }
    }
}

// ---------------------------------------------------------------------------
// Merged: f32->bf16 convert of x (blocks 0..2047, grid-stride) +
// embeds gather (blocks 2048..4287, 8 rows each).
// ---------------------------------------------------------------------------
__global__ __launch_bounds__(256)
void conv_x_embed(const float* __restrict__ in, unsigned short* __restrict__ out,
                  int n8, const float* __restrict__ embeds,
                  const int* __restrict__ tgt_y, unsigned short* __restrict__ yb)
{
    if (blockIdx.x < 2048) {
        for (int i = blockIdx.x * 256 + threadIdx.x; i < n8; i += 2048 * 256) {
            float4 a = ((const float4*)in)[i * 2];
            float4 b = ((const float4*)in)[i * 2 + 1];
            us8 o = { f2bf(a.x), f2bf(a.y), f2bf(a.z), f2bf(a.w),
                      f2bf(b.x), f2bf(b.y), f2bf(b.z), f2bf(b.w) };
            ((us8*)out)[i] = o;
        }
    } else {
        const int i = (blockIdx.x - 2048) * 8 + (threadIdx.x >> 5);
        const int c8 = (threadIdx.x & 31) * 8;
        const int v = tgt_y[i];
        const float* p = embeds + (size_t)v * 256 + c8;
        float4 a = *(const float4*)p;
        float4 b = *(const float4*)(p + 4);
        us8 o = { f2bf(a.x), f2bf(a.y), f2bf(a.z), f2bf(a.w),
                  f2bf(b.x), f2bf(b.y), f2bf(b.z), f2bf(b.w) };
        *(us8*)(yb + (size_t)i * 256 + c8) = o;
    }
}

// ---------------------------------------------------------------------------
// All weight transposes in ONE dispatch. Grid (8, 8, 10); out-of-range exit.
// ---------------------------------------------------------------------------
struct WAll {
    const float* src[10];
    unsigned short* dst[10];
    int R[10];
    int C[10];
};

__global__ __launch_bounds__(256)
void conv_wT_all(WAll d)
{
    const int z = blockIdx.z;
    const int R = d.R[z], C = d.C[z];
    const int c0 = blockIdx.x * 64, r0 = blockIdx.y * 64;
    if (c0 >= C || r0 >= R) return;
    const float* in = d.src[z];
    unsigned short* outT = d.dst[z];
    __shared__ unsigned short t[64][65];
    const int r = threadIdx.x >> 4, cq = (threadIdx.x & 15) << 2;
#pragma unroll
    for (int i = 0; i < 4; ++i) {
        const int rr = r + i * 16;
        float4 v = *(const float4*)(in + (size_t)(r0 + rr) * C + c0 + cq);
        t[rr][cq + 0] = f2bf(v.x); t[rr][cq + 1] = f2bf(v.y);
        t[rr][cq + 2] = f2bf(v.z); t[rr][cq + 3] = f2bf(v.w);
    }
    __syncthreads();
    const int c = threadIdx.x >> 2, sq = (threadIdx.x & 3) << 4;
    us8 o0, o1;
#pragma unroll
    for (int i = 0; i < 8; ++i) { o0[i] = t[sq + i][c]; o1[i] = t[sq + 8 + i][c]; }
    *(us8*)(outT + (size_t)(c0 + c) * R + r0 + sq) = o0;
    *(us8*)(outT + (size_t)(c0 + c) * R + r0 + sq + 8) = o1;
}

// ---------------------------------------------------------------------------
// CSR build (4 small parallel dispatches — proven fast)
// ---------------------------------------------------------------------------
__global__ __launch_bounds__(256)
void edge_deg(const int* __restrict__ tgt, int* __restrict__ deg)
{
    const int e = blockIdx.x * 256 + threadIdx.x;
    if (e < NE_) atomicAdd(&deg[tgt[e]], 1);
}

__global__ __launch_bounds__(1024)
void scan_off(const int* __restrict__ deg, int* __restrict__ off, int* __restrict__ cursor)
{
    __shared__ int ls[1024];
    const int t = threadIdx.x;
    const int base = t * 18;
    int local[18];
    int s = 0;
#pragma unroll
    for (int i = 0; i < 18; ++i) {
        const int idx = base + i;
        const int v = (idx < NY_) ? deg[idx] : 0;
        local[i] = s; s += v;
    }
    ls[t] = s;
    __syncthreads();
    for (int d = 1; d < 1024; d <<= 1) {
        int v = (t >= d) ? ls[t - d] : 0;
        __syncthreads();
        ls[t] += v;
        __syncthreads();
    }
    const int excl = (t == 0) ? 0 : ls[t - 1];
#pragma unroll
    for (int i = 0; i < 18; ++i) {
        const int idx = base + i;
        if (idx < NY_) {
            const int o = excl + local[i];
            off[idx] = o; cursor[idx] = o;
        }
    }
    if (t == 1023) off[NY_] = ls[1023];
}

__global__ __launch_bounds__(256)
void edge_fill(const int* __restrict__ tgt, int* __restrict__ cursor,
               int* __restrict__ elist)
{
    const int e = blockIdx.x * 256 + threadIdx.x;
    if (e >= NE_) return;
    const int pos = atomicAdd(&cursor[tgt[e]], 1);
    elist[pos] = e;
}

// ---------------------------------------------------------------------------
// aggb[t,:] = bf16( hb[t,:] + sum_{e in bucket(t)} hb[src[e],:] + cnt * Ee )
// ---------------------------------------------------------------------------
__global__ __launch_bounds__(256)
void node_agg(const unsigned short* __restrict__ hb,
              const float* __restrict__ Ee,
              const int* __restrict__ src, const int* __restrict__ etype,
              const int* __restrict__ off, const int* __restrict__ elist,
              unsigned short* __restrict__ aggb)
{
    const int nid  = blockIdx.x * 4 + (threadIdx.x >> 6);
    const int lane = threadIdx.x & 63;
    const int c = lane * 4;
    const int k0 = off[nid], k1 = off[nid + 1];
    us4 sv = *(const us4*)(hb + (size_t)nid * 256 + c);
    float4 acc;
    acc.x = bf2f(sv[0]); acc.y = bf2f(sv[1]);
    acc.z = bf2f(sv[2]); acc.w = bf2f(sv[3]);
    int cnt0 = 0, cnt1 = 0, cnt2 = 0, cnt3 = 0;
    for (int k = k0; k < k1; ++k) {
        const int e = elist[k];
        const int sfrom = src[e];
        const int ty = etype[e];
        us4 hv = *(const us4*)(hb + (size_t)sfrom * 256 + c);
        acc.x += bf2f(hv[0]); acc.y += bf2f(hv[1]);
        acc.z += bf2f(hv[2]); acc.w += bf2f(hv[3]);
        cnt0 += (ty == 0); cnt1 += (ty == 1); cnt2 += (ty == 2); cnt3 += (ty == 3);
    }
    float4 e0 = *(const float4*)(Ee + c);
    float4 e1 = *(const float4*)(Ee + 256 + c);
    float4 e2 = *(const float4*)(Ee + 512 + c);
    float4 e3 = *(const float4*)(Ee + 768 + c);
    acc.x += cnt0 * e0.x + cnt1 * e1.x + cnt2 * e2.x + cnt3 * e3.x;
    acc.y += cnt0 * e0.y + cnt1 * e1.y + cnt2 * e2.y + cnt3 * e3.y;
    acc.z += cnt0 * e0.z + cnt1 * e1.z + cnt2 * e2.z + cnt3 * e3.z;
    acc.w += cnt0 * e0.w + cnt1 * e1.w + cnt2 * e2.w + cnt3 * e3.w;
    us4 o = { f2bf(acc.x), f2bf(acc.y), f2bf(acc.z), f2bf(acc.w) };
    *(us4*)(aggb + (size_t)nid * 256 + c) = o;
}

// ---------------------------------------------------------------------------
// esc[e,0:8] = Y12[src[e],0:8] + Y12[tgt[e],8:16] + b
// ---------------------------------------------------------------------------
__global__ __launch_bounds__(256)
void edge_gather(const float* __restrict__ Y12, const int* __restrict__ src,
                 const int* __restrict__ tgt, const float* __restrict__ bias,
                 float* __restrict__ esc)
{
    const int e = blockIdx.x * 256 + threadIdx.x;
    if (e >= NE_) return;
    const float* a = Y12 + (size_t)src[e] * 16;
    const float* b = Y12 + (size_t)tgt[e] * 16 + 8;
    float4 a0 = ((const float4*)a)[0], a1 = ((const float4*)a)[1];
    float4 b0 = ((const float4*)b)[0], b1 = ((const float4*)b)[1];
    float4 c0 = ((const float4*)bias)[0], c1 = ((const float4*)bias)[1];
    float4 o0, o1;
    o0.x = a0.x + b0.x + c0.x; o0.y = a0.y + b0.y + c0.y;
    o0.z = a0.z + b0.z + c0.z; o0.w = a0.w + b0.w + c0.w;
    o1.x = a1.x + b1.x + c1.x; o1.y = a1.y + b1.y + c1.y;
    o1.z = a1.z + b1.z + c1.z; o1.w = a1.w + b1.w + c1.w;
    ((float4*)(esc + (size_t)e * 8))[0] = o0;
    ((float4*)(esc + (size_t)e * 8))[1] = o1;
}

// ---------------------------------------------------------------------------
extern "C" void kernel_launch(void* const* d_in, const int* in_sizes, int n_in,
                              void* d_out, int out_size, void* d_ws, size_t ws_size,
                              hipStream_t stream)
{
    const float* x       = (const float*)d_in[0];
    const int*   tgt_y   = (const int*)d_in[2];
    const int*   eidx    = (const int*)d_in[3];
    const int*   etype   = (const int*)d_in[4];
    const float* embeds  = (const float*)d_in[6];
    const float* W_in[3] = {(const float*)d_in[7],  (const float*)d_in[11], (const float*)d_in[15]};
    const float* Wq[3]   = {(const float*)d_in[8],  (const float*)d_in[12], (const float*)d_in[16]};
    const float* Wv[3]   = {(const float*)d_in[9],  (const float*)d_in[13], (const float*)d_in[17]};
    const float* Ee[3]   = {(const float*)d_in[10], (const float*)d_in[14], (const float*)d_in[18]};
    const float* lin_z_w = (const float*)d_in[19];
    const float* lin_z_b = (const float*)d_in[20];
    const float* lin_g_w = (const float*)d_in[21];
    const float* lin_g_b = (const float*)d_in[22];
    const int* src = eidx;
    const int* tgt = eidx + NE_;

    float* out = (float*)d_out;
    // d_out layout (floats)
    float* y_final = out;                        // [17920][256]
    float* score   = out + 4587520;              // [17920][256]
    float* esc     = out + 9175040;              // [71680][8]
    float* aout[3] = {out + 9748480, out + 14336000, out + 18923520}; // [B][70][256]

    // workspace layout (bytes)
    char* wsb = (char*)d_ws;
    unsigned short* xb     = (unsigned short*)(wsb + 0);            //  67,108,864
    unsigned short* xvTall = (unsigned short*)(wsb + 67108864);     // 100,663,296  [B][768][256]
    unsigned short* hb     = (unsigned short*)(wsb + 167772160);    //   9,175,040
    unsigned short* aggb   = (unsigned short*)(wsb + 176947200);    //   9,175,040
    unsigned short* qb     = (unsigned short*)(wsb + 186122240);    //  18,350,080
    unsigned short* yb     = (unsigned short*)(wsb + 204472320);    //   9,175,040
    char* wt = wsb + 213647360;                                     //   2,883,584
    // wcatT[l]: [768][256] bf16 (rows 0-255 = W_in^T, rows 256-767 = (W_in@Wq)^T)
    unsigned short* wcatT[3], *wqT[3], *wvT[3];
    for (int l = 0; l < 3; ++l) {
        wcatT[l] = (unsigned short*)(wt + l * 393216);
        wqT[l]   = (unsigned short*)(wt + 1179648 + l * 262144);
        wvT[l]   = (unsigned short*)(wt + 1966080 + l * 262144);  // contiguous x3 = [768][512]
    }
    unsigned short* lzT = (unsigned short*)(wt + 2752512);
    char* extra = wsb + 216530944;
    float* Y12    = (float*)extra;                 // 1,146,880
    int*   deg    = (int*)(extra + 1146880);       //    71,680
    int*   off    = (int*)(extra + 1218560);       //    71,684
    int*   cursor = (int*)(extra + 1290244);       //    71,680
    int*   elist  = (int*)(extra + 1361924);       //   286,720

    // --- CSR build (parallel 4-dispatch pipeline) ---
    hipMemsetAsync(deg, 0, NY_ * sizeof(int), stream);
    edge_deg<<<280, 256, 0, stream>>>(tgt, deg);
    scan_off<<<1, 1024, 0, stream>>>(deg, off, cursor);
    edge_fill<<<280, 256, 0, stream>>>(tgt, cursor, elist);

    // --- one-time conversions ---
    conv_x_embed<<<4288, 256, 0, stream>>>(x, xb, 4194304, embeds, tgt_y, yb);
    WAll wd;
    for (int l = 0; l < 3; ++l) {
        wd.src[l]     = W_in[l]; wd.dst[l]     = wcatT[l]; wd.R[l]     = 256; wd.C[l]     = 256;
        wd.src[3 + l] = Wq[l];   wd.dst[3 + l] = wqT[l];   wd.R[3 + l] = 256; wd.C[3 + l] = 512;
        wd.src[6 + l] = Wv[l];   wd.dst[6 + l] = wvT[l];   wd.R[6 + l] = 512; wd.C[6 + l] = 256;
    }
    wd.src[9] = lin_z_w; wd.dst[9] = lzT; wd.R[9] = 256; wd.C[9] = 256;
    conv_wT_all<<<dim3(8, 8, 10), 256, 0, stream>>>(wd);

    // --- wcatT rows 256-767 = (W_in@Wq)^T = Wq^T @ W_in^T  (batched z=3) ---
    gemm_mfma<0, 0><<<dim3(2, 4, 3), 256, 0, stream>>>(
        wqT[0], 256, 131072L,  wcatT[0], 256, 196608L,
        nullptr, 0, 0,  wcatT[0] + 65536, 256, 196608L,
        512, 256, 1.f, 0, 0);

    // --- xvTall[b] = [Wv1;Wv2;Wv3]^T-concat @ x_b^T : [768][256] per batch ---
    gemm_mfma<0, 1><<<3072, 256, 0, stream>>>(
        wvT[0], 512, 0,  xb, 512, (long)SX_ * F_,
        nullptr, 0, 0,  xvTall, 256, 768L * 256,
        768, 512, 1.f, 2, 6);

    const float qscale = 0.044194173824159216f;  // 1/sqrt(512)
    for (int l = 0; l < 3; ++l) {
        // [h|q] = y @ Wcat : cols 0-255 -> hb (bf16), cols 256-767 -> qb (bf16)
        gemm_mfma<7, 0><<<dim3(6, 140, 1), 256, 0, stream>>>(
            yb, 256, 0,  wcatT[l], 256, 0,
            (float*)qb, 512, 0,  hb, 256, 0,
            NY_, 256, 1.f, 0, 0);
        // aggb = bf16(h + segment_sum(h[src] + Ee[etype], tgt))
        node_agg<<<4480, 256, 0, stream>>>(hb, Ee[l], src, etype, off, elist, aggb);
        // fused attn (half-batch split, 2 blocks/CU)
        if (l < 2) {
            attn_pv<0><<<512, 256, 0, stream>>>(
                qb, xb, xvTall + (size_t)l * 65536, 768L * 256,
                aggb, nullptr, nullptr, nullptr, nullptr,
                aout[l], yb, nullptr, nullptr, qscale);
        } else {
            attn_pv<1><<<512, 256, 0, stream>>>(
                qb, xb, xvTall + (size_t)l * 65536, 768L * 256,
                aggb, lzT, lin_z_b, lin_g_w, Y12,
                aout[l], yb, y_final, score, qscale);
        }
    }
    // edge relation scores from Y12
    edge_gather<<<280, 256, 0, stream>>>(Y12, src, tgt, lin_g_b, esc);
}

// Round 26
// 417.872 us; speedup vs baseline: 1.0677x; 1.0437x over previous
//
#include <hip/hip_runtime.h>
#include <cstddef>
#include <cstdint>

#define B_    256
#define SX_   256
#define SY_   70
#define F_    512
#define EMB_  256
#define NY_   (B_*SY_)     // 17920
#define NE_   (4*B_*SY_)   // 71680

typedef short s16x8 __attribute__((ext_vector_type(8)));   // MFMA A/B frag (8 bf16)
typedef float f32x4 __attribute__((ext_vector_type(4)));   // MFMA C/D frag
typedef unsigned short us4 __attribute__((ext_vector_type(4)));
typedef unsigned short us8 __attribute__((ext_vector_type(8)));

__device__ __forceinline__ unsigned short f2bf(float f) {
    unsigned u = __builtin_bit_cast(unsigned, f);
    u += 0x7fffu + ((u >> 16) & 1u);          // RNE
    return (unsigned short)(u >> 16);
}
__device__ __forceinline__ float bf2f(unsigned short b) {
    unsigned u = ((unsigned)b) << 16;
    return __builtin_bit_cast(float, u);
}

// ---------------------------------------------------------------------------
// Unified bf16 MFMA GEMM, C = A @ Bt^T. A:[M][K] bf16, Bt:[N][K] bf16.
// 128x128 tile, BK=64, 4 waves (2x2 of 64x64), 16x16x32 MFMA.
// EPI: 0 = plain; 4 = acc + f32 aux[col] (bias);
//      7 = dual-bf16 split: col<256 -> Cb (ld 256), col>=256 -> (ushort*)Cf (ld 512)
// SWZ: 1 = flattened 1D grid with bijective XCD remap (gridDim.x % 8 == 0).
// ---------------------------------------------------------------------------
template<int EPI, int SWZ>
__global__ __launch_bounds__(256, 2)
void gemm_mfma(const unsigned short* __restrict__ A, int lda, long sAb,
               const unsigned short* __restrict__ Bt, int ldb, long sBb,
               float* __restrict__ Cf, int ldc, long sCfb,
               unsigned short* __restrict__ Cb, int ldcb, long sCbb,
               const float* __restrict__ aux1, long sAux,
               int M, int K, float scale, int nx, int ny)
{
    __shared__ unsigned short As[128 * 64];
    __shared__ unsigned short Bs[128 * 64];
    char* AsB = (char*)As;
    char* BsB = (char*)Bs;
    const int tid = threadIdx.x;
    int bxi, byi, z;
    if (SWZ) {
        const int nwg = gridDim.x;
        const int bid = blockIdx.x;
        const int wg = (bid & 7) * (nwg >> 3) + (bid >> 3);
        bxi = wg % nx;
        byi = (wg / nx) % ny;
        z   = wg / (nx * ny);
    } else {
        bxi = blockIdx.x; byi = blockIdx.y; z = blockIdx.z;
    }
    A  += (size_t)z * sAb;
    Bt += (size_t)z * sBb;
    const char* auxp = (const char*)aux1 + (size_t)z * sAux;
    const int bm = byi * 128, bn = bxi * 128;
    const int lane = tid & 63;
    const int w = tid >> 6, wr = w >> 1, wc = w & 1;
    const int l15 = lane & 15, lq = lane >> 4;

    f32x4 acc[4][4];
    const f32x4 z4 = {0.f, 0.f, 0.f, 0.f};
#pragma unroll
    for (int m = 0; m < 4; ++m)
#pragma unroll
        for (int n = 0; n < 4; ++n) acc[m][n] = z4;

    for (int k0 = 0; k0 < K; k0 += 64) {
#pragma unroll
        for (int i = 0; i < 4; ++i) {
            const int row = i * 32 + (tid >> 3);
            const int k8  = (tid & 7) ^ (row & 7);
            int ra = bm + row; ra = (ra < M) ? ra : (M - 1);
            const unsigned short* g = A + (size_t)ra * lda + k0 + k8 * 8;
            __builtin_amdgcn_global_load_lds(
                (const __attribute__((address_space(1))) unsigned int*)g,
                (__attribute__((address_space(3))) unsigned int*)(AsB + i * 4096 + tid * 16),
                16, 0, 0);
        }
#pragma unroll
        for (int i = 0; i < 4; ++i) {
            const int row = i * 32 + (tid >> 3);
            const int k8  = (tid & 7) ^ (row & 7);
            const unsigned short* g = Bt + (size_t)(bn + row) * ldb + k0 + k8 * 8;
            __builtin_amdgcn_global_load_lds(
                (const __attribute__((address_space(1))) unsigned int*)g,
                (__attribute__((address_space(3))) unsigned int*)(BsB + i * 4096 + tid * 16),
                16, 0, 0);
        }
        __syncthreads();
#pragma unroll
        for (int kk = 0; kk < 2; ++kk) {
            s16x8 af[4], bf[4];
#pragma unroll
            for (int m = 0; m < 4; ++m) {
                const int row = wr * 64 + m * 16 + l15;
                const int slot = (kk * 4 + lq) ^ (row & 7);
                af[m] = *(const s16x8*)(AsB + row * 128 + slot * 16);
            }
#pragma unroll
            for (int n = 0; n < 4; ++n) {
                const int col = wc * 64 + n * 16 + l15;
                const int slot = (kk * 4 + lq) ^ (col & 7);
                bf[n] = *(const s16x8*)(BsB + col * 128 + slot * 16);
            }
#pragma unroll
            for (int m = 0; m < 4; ++m)
#pragma unroll
                for (int n = 0; n < 4; ++n)
                    acc[m][n] = __builtin_amdgcn_mfma_f32_16x16x32_bf16(
                        af[m], bf[n], acc[m][n], 0, 0, 0);
        }
        __syncthreads();
    }

    float* cf = Cf ? Cf + (size_t)z * sCfb : nullptr;
    unsigned short* cb = Cb ? Cb + (size_t)z * sCbb : nullptr;
#pragma unroll
    for (int m = 0; m < 4; ++m) {
#pragma unroll
        for (int n = 0; n < 4; ++n) {
            const int col = bn + wc * 64 + n * 16 + l15;
            f32x4 v = acc[m][n];
#pragma unroll
            for (int r = 0; r < 4; ++r) {
                const int gr = bm + wr * 64 + m * 16 + lq * 4 + r;
                if (gr >= M) continue;
                float o = v[r] * scale;
                if (EPI == 4) o += ((const float*)auxp)[col];
                if (EPI == 7) {
                    if (col < 256) cb[(size_t)gr * ldcb + col] = f2bf(o);
                    else ((unsigned short*)cf)[(size_t)gr * 512 + (col - 256)] = f2bf(o);
                } else {
                    if (cf) cf[(size_t)gr * ldc + col] = o;
                    if (cb) cb[(size_t)gr * ldcb + col] = f2bf(o);
                }
            }
        }
    }
}

// ---------------------------------------------------------------------------
// Fused attention layer kernel, one block per batch (grid 256, 8 waves).
// Phase 1: S = scale*Q@X^T (counted-vmcnt pipeline, BK=32, 3 bufs).
// Middle: softmax; alpha bf16 -> Al (swizzled); VECTORIZED alpha dump to Aout.
// Phase 2: O = alpha @ xv; O bf16 -> Al; VECTORIZED y dump
//          (y = relu(O + aggb) -> Yb/Yf, y also back into Al).
// Phase 3 (LAST): score = y @ lzT + lzb.  Phase 4 (LAST): Y12 = y @ gw.
// ---------------------------------------------------------------------------
template<int LAST>
__global__ __launch_bounds__(512, 1)
void attn_pv(const unsigned short* __restrict__ Q,    // [B][70][512]
             const unsigned short* __restrict__ X,    // [B][256][512]
             const unsigned short* __restrict__ XV,   // [B][768][256] (layer slice)
             long sXVb,
             const unsigned short* __restrict__ aggb, // [17920][256] bf16
             const unsigned short* __restrict__ lzT,  // [256][256] bf16 (LAST)
             const float* __restrict__ lzb,           // [256] f32 (LAST)
             const float* __restrict__ gw,            // [512][8] f32 (LAST)
             float* __restrict__ Y12g,                // [17920][16] f32 (LAST)
             float* __restrict__ Aout,                // [B][70][256]
             unsigned short* __restrict__ Yb,         // [17920][256] bf16
             float* __restrict__ Yf,                  // f32 or null
             float* __restrict__ Score,               // [17920][256] f32 (LAST)
             float scale)
{
    __shared__ unsigned short SB[3 * 12288];  // 72 KB: ph1 3x24KB; ph2/3 2x32KB
    __shared__ unsigned short Al[128 * 256];  // 64 KB (alpha / O / y, swizzled)
    __shared__ float red[4][2][64];
    char* SBb = (char*)SB;
    char* AlB = (char*)Al;
    const int tid = threadIdx.x;
    const int z = blockIdx.x;
    const unsigned short* Qb  = Q + (size_t)z * SY_ * F_;
    const unsigned short* Xb  = X + (size_t)z * SX_ * F_;
    const unsigned short* xvb = XV + (size_t)z * sXVb;
    const int lane = tid & 63;
    const int w = tid >> 6, wr = w >> 2, wc = w & 3;
    const int l15 = lane & 15, lq = lane >> 4;

    // ---- phase 1: counted-vmcnt pipeline, BK=32, 16 steps, 3 bufs ----
    auto stage1 = [&](int t) {
        char* base = SBb + (t % 3) * 24576;
        {
            const int row = tid >> 2;
            const int k8  = (tid & 3) ^ ((row >> 1) & 3);
            const int ra = (row < SY_) ? row : (SY_ - 1);
            const unsigned short* g = Qb + (size_t)ra * F_ + t * 32 + k8 * 8;
            __builtin_amdgcn_global_load_lds(
                (const __attribute__((address_space(1))) unsigned int*)g,
                (__attribute__((address_space(3))) unsigned int*)(base + tid * 16),
                16, 0, 0);
        }
#pragma unroll
        for (int i = 0; i < 2; ++i) {
            const int row = i * 128 + (tid >> 2);
            const int k8  = (tid & 3) ^ ((row >> 1) & 3);
            const unsigned short* g = Xb + (size_t)row * F_ + t * 32 + k8 * 8;
            __builtin_amdgcn_global_load_lds(
                (const __attribute__((address_space(1))) unsigned int*)g,
                (__attribute__((address_space(3))) unsigned int*)(base + 8192 + i * 8192 + tid * 16),
                16, 0, 0);
        }
    };

    f32x4 acc[4][4];
    const f32x4 z4 = {0.f, 0.f, 0.f, 0.f};
#pragma unroll
    for (int m = 0; m < 4; ++m)
#pragma unroll
        for (int n = 0; n < 4; ++n) acc[m][n] = z4;

    stage1(0);
    stage1(1);
    for (int t = 0; t < 16; ++t) {
        if (t + 2 < 16) stage1(t + 2);
        if (t < 14)       asm volatile("s_waitcnt vmcnt(6)" ::: "memory");
        else if (t == 14) asm volatile("s_waitcnt vmcnt(3)" ::: "memory");
        else              asm volatile("s_waitcnt vmcnt(0)" ::: "memory");
        __builtin_amdgcn_s_barrier();
        asm volatile("" ::: "memory");
        char* base = SBb + (t % 3) * 24576;
        s16x8 af[4], bf[4];
#pragma unroll
        for (int m = 0; m < 4; ++m) {
            const int row = wr * 64 + m * 16 + l15;
            const int slot = lq ^ ((row >> 1) & 3);
            af[m] = *(const s16x8*)(base + row * 64 + slot * 16);
        }
#pragma unroll
        for (int n = 0; n < 4; ++n) {
            const int col = wc * 64 + n * 16 + l15;
            const int slot = lq ^ ((col >> 1) & 3);
            bf[n] = *(const s16x8*)(base + 8192 + col * 64 + slot * 16);
        }
#pragma unroll
        for (int m = 0; m < 4; ++m)
#pragma unroll
            for (int n = 0; n < 4; ++n)
                acc[m][n] = __builtin_amdgcn_mfma_f32_16x16x32_bf16(
                    af[m], bf[n], acc[m][n], 0, 0, 0);
        asm volatile("" ::: "memory");
        __builtin_amdgcn_s_barrier();
    }

    // ---- softmax ----
#pragma unroll
    for (int m = 0; m < 4; ++m)
#pragma unroll
        for (int n = 0; n < 4; ++n)
#pragma unroll
            for (int r = 0; r < 4; ++r) acc[m][n][r] *= scale;

    float rmax[4][4];
#pragma unroll
    for (int m = 0; m < 4; ++m)
#pragma unroll
        for (int r = 0; r < 4; ++r) {
            float mx = acc[m][0][r];
#pragma unroll
            for (int n = 1; n < 4; ++n) mx = fmaxf(mx, acc[m][n][r]);
            mx = fmaxf(mx, __shfl_xor(mx, 1));
            mx = fmaxf(mx, __shfl_xor(mx, 2));
            mx = fmaxf(mx, __shfl_xor(mx, 4));
            mx = fmaxf(mx, __shfl_xor(mx, 8));
            rmax[m][r] = mx;
        }
    if (l15 == 0) {
#pragma unroll
        for (int m = 0; m < 4; ++m)
#pragma unroll
            for (int r = 0; r < 4; ++r)
                red[wc][wr][m * 16 + lq * 4 + r] = rmax[m][r];
    }
    __syncthreads();
    float rtot[4][4];
#pragma unroll
    for (int m = 0; m < 4; ++m)
#pragma unroll
        for (int r = 0; r < 4; ++r) {
            const int lr = m * 16 + lq * 4 + r;
            rtot[m][r] = fmaxf(fmaxf(red[0][wr][lr], red[1][wr][lr]),
                               fmaxf(red[2][wr][lr], red[3][wr][lr]));
        }
    __syncthreads();
    float rsum[4][4];
#pragma unroll
    for (int m = 0; m < 4; ++m)
#pragma unroll
        for (int r = 0; r < 4; ++r) {
            float s = 0.f;
#pragma unroll
            for (int n = 0; n < 4; ++n) {
                float e = __expf(acc[m][n][r] - rtot[m][r]);
                acc[m][n][r] = e;
                s += e;
            }
            s += __shfl_xor(s, 1);
            s += __shfl_xor(s, 2);
            s += __shfl_xor(s, 4);
            s += __shfl_xor(s, 8);
            rsum[m][r] = s;
        }
    if (l15 == 0) {
#pragma unroll
        for (int m = 0; m < 4; ++m)
#pragma unroll
            for (int r = 0; r < 4; ++r)
                red[wc][wr][m * 16 + lq * 4 + r] = rsum[m][r];
    }
    __syncthreads();
    // ---- alpha: bf16 -> LDS Al (swizzled) only ----
#pragma unroll
    for (int m = 0; m < 4; ++m)
#pragma unroll
        for (int r = 0; r < 4; ++r) {
            const int lr = m * 16 + lq * 4 + r;
            const int row = wr * 64 + lr;
            const float inv = 1.0f / (red[0][wr][lr] + red[1][wr][lr] +
                                      red[2][wr][lr] + red[3][wr][lr]);
#pragma unroll
            for (int n = 0; n < 4; ++n) {
                const int col = wc * 64 + n * 16 + l15;
                *(unsigned short*)(AlB + row * 512 +
                    (((col >> 3) ^ (row & 7)) << 4) + ((col & 7) << 1))
                    = f2bf(acc[m][n][r] * inv);
            }
        }
    __syncthreads();
    // ---- vectorized alpha dump: Al bf16 -> Aout f32 (rows < 70) ----
    {
        float* ao = Aout + (size_t)z * SY_ * SX_;
        for (int idx = tid; idx < SY_ * 8; idx += 512) {
            const int row = idx >> 3, seg = idx & 7;
            float tmp[32];
#pragma unroll
            for (int c8 = 0; c8 < 4; ++c8) {
                const int chunk = seg * 4 + c8;
                us8 v = *(const us8*)(AlB + row * 512 + ((chunk ^ (row & 7)) << 4));
#pragma unroll
                for (int j = 0; j < 8; ++j) tmp[c8 * 8 + j] = bf2f(v[j]);
            }
            float* dst = ao + (size_t)row * SX_ + seg * 32;
#pragma unroll
            for (int q = 0; q < 8; ++q) {
                float4 o4; o4.x = tmp[q*4]; o4.y = tmp[q*4+1];
                o4.z = tmp[q*4+2]; o4.w = tmp[q*4+3];
                ((float4*)dst)[q] = o4;
            }
        }
    }

    // ---- phase 2: O = alpha @ xv  (K = 256, BK=64, dbuf + syncthreads) ----
    char* v_buf[2] = {SBb, SBb + 32768};
    auto stage2 = [&](int k0, int buf, const unsigned short* srcm) {
        char* bb = v_buf[buf];
#pragma unroll
        for (int i = 0; i < 4; ++i) {
            const int row = i * 64 + (tid >> 3);
            const int k8  = (tid & 7) ^ (row & 7);
            const unsigned short* g = srcm + (size_t)row * 256 + k0 + k8 * 8;
            __builtin_amdgcn_global_load_lds(
                (const __attribute__((address_space(1))) unsigned int*)g,
                (__attribute__((address_space(3))) unsigned int*)(bb + i * 8192 + tid * 16),
                16, 0, 0);
        }
    };

    f32x4 oac[4][4];
#pragma unroll
    for (int m = 0; m < 4; ++m)
#pragma unroll
        for (int n = 0; n < 4; ++n) oac[m][n] = z4;

    stage2(0, 0, xvb);
    __syncthreads();
    int cur = 0;
    for (int ks = 0; ks < 4; ++ks) {
        if (ks < 3) stage2((ks + 1) * 64, cur ^ 1, xvb);
        char* bb = v_buf[cur];
        const int k0 = ks * 64;
#pragma unroll
        for (int kk = 0; kk < 2; ++kk) {
            s16x8 af[4], bf[4];
#pragma unroll
            for (int m = 0; m < 4; ++m) {
                const int row = wr * 64 + m * 16 + l15;
                const int chunk = (k0 >> 3) + kk * 4 + lq;
                af[m] = *(const s16x8*)(AlB + row * 512 + ((chunk ^ (row & 7)) << 4));
            }
#pragma unroll
            for (int n = 0; n < 4; ++n) {
                const int col = wc * 64 + n * 16 + l15;
                const int slot = (kk * 4 + lq) ^ (col & 7);
                bf[n] = *(const s16x8*)(bb + col * 128 + slot * 16);
            }
#pragma unroll
            for (int m = 0; m < 4; ++m)
#pragma unroll
                for (int n = 0; n < 4; ++n)
                    oac[m][n] = __builtin_amdgcn_mfma_f32_16x16x32_bf16(
                        af[m], bf[n], oac[m][n], 0, 0, 0);
        }
        __syncthreads();
        cur ^= 1;
    }

    // ---- O bf16 -> Al (rows < 70) ----
#pragma unroll
    for (int m = 0; m < 4; ++m)
#pragma unroll
        for (int n = 0; n < 4; ++n) {
            const int col = wc * 64 + n * 16 + l15;
            f32x4 v = oac[m][n];
#pragma unroll
            for (int r = 0; r < 4; ++r) {
                const int row = wr * 64 + m * 16 + lq * 4 + r;
                if (row >= SY_) continue;
                *(unsigned short*)(AlB + row * 512 +
                    (((col >> 3) ^ (row & 7)) << 4) + ((col & 7) << 1)) = f2bf(v[r]);
            }
        }
    __syncthreads();
    // ---- vectorized y dump: y = relu(O + aggb) -> Yb (+Yf), y -> Al ----
    {
        const size_t nodeBase = (size_t)z * SY_;
        for (int idx = tid; idx < SY_ * 8; idx += 512) {
            const int row = idx >> 3, seg = idx & 7;
            const size_t node = nodeBase + row;
            float tmp[32];
#pragma unroll
            for (int c8 = 0; c8 < 4; ++c8) {
                const int chunk = seg * 4 + c8;
                us8 ov = *(const us8*)(AlB + row * 512 + ((chunk ^ (row & 7)) << 4));
                us8 av = *(const us8*)(aggb + node * 256 + seg * 32 + c8 * 8);
                us8 o;
#pragma unroll
                for (int j = 0; j < 8; ++j) {
                    float val = fmaxf(bf2f(ov[j]) + bf2f(av[j]), 0.f);
                    tmp[c8 * 8 + j] = val;
                    o[j] = f2bf(val);
                }
                *(us8*)(Yb + node * 256 + seg * 32 + c8 * 8) = o;
                if (LAST)
                    *(us8*)(AlB + row * 512 + ((chunk ^ (row & 7)) << 4)) = o;
            }
            if (Yf) {
                float* dst = Yf + node * 256 + seg * 32;
#pragma unroll
                for (int q = 0; q < 8; ++q) {
                    float4 o4; o4.x = tmp[q*4]; o4.y = tmp[q*4+1];
                    o4.z = tmp[q*4+2]; o4.w = tmp[q*4+3];
                    ((float4*)dst)[q] = o4;
                }
            }
        }
    }

    if (LAST) {
        __syncthreads();
        // ---- phase 3: score = y @ lzT + lzb  (K = 256, dbuf) ----
#pragma unroll
        for (int m = 0; m < 4; ++m)
#pragma unroll
            for (int n = 0; n < 4; ++n) oac[m][n] = z4;
        stage2(0, 0, lzT);
        __syncthreads();
        cur = 0;
        for (int ks = 0; ks < 4; ++ks) {
            if (ks < 3) stage2((ks + 1) * 64, cur ^ 1, lzT);
            char* bb = v_buf[cur];
            const int k0 = ks * 64;
#pragma unroll
            for (int kk = 0; kk < 2; ++kk) {
                s16x8 af[4], bf[4];
#pragma unroll
                for (int m = 0; m < 4; ++m) {
                    const int row = wr * 64 + m * 16 + l15;
                    const int chunk = (k0 >> 3) + kk * 4 + lq;
                    af[m] = *(const s16x8*)(AlB + row * 512 + ((chunk ^ (row & 7)) << 4));
                }
#pragma unroll
                for (int n = 0; n < 4; ++n) {
                    const int col = wc * 64 + n * 16 + l15;
                    const int slot = (kk * 4 + lq) ^ (col & 7);
                    bf[n] = *(const s16x8*)(bb + col * 128 + slot * 16);
                }
#pragma unroll
                for (int m = 0; m < 4; ++m)
#pragma unroll
                    for (int n = 0; n < 4; ++n)
                        oac[m][n] = __builtin_amdgcn_mfma_f32_16x16x32_bf16(
                            af[m], bf[n], oac[m][n], 0, 0, 0);
            }
            __syncthreads();
            cur ^= 1;
        }
#pragma unroll
        for (int m = 0; m < 4; ++m)
#pragma unroll
            for (int n = 0; n < 4; ++n) {
                const int col = wc * 64 + n * 16 + l15;
                f32x4 v = oac[m][n];
#pragma unroll
                for (int r = 0; r < 4; ++r) {
                    const int row = wr * 64 + m * 16 + lq * 4 + r;
                    if (row >= SY_) continue;
                    Score[((size_t)z * SY_ + row) * 256 + col] = v[r] + lzb[col];
                }
            }

        // ---- phase 4: Y12 = y @ [gw0|gw1]  (70 x 16, K = 256) ----
        __syncthreads();
        float* Ws = (float*)SBb;
        for (int i = tid; i < 1024; i += 512)
            ((float4*)Ws)[i] = ((const float4*)gw)[i];
        __syncthreads();
        for (int t = tid; t < 1120; t += 512) {
            const int row = t >> 4, j = t & 15;
            const float* Wcol = Ws + ((j < 8) ? j : (2048 + j - 8));
            float a2 = 0.f;
            for (int c = 0; c < 256; ++c) {
                const float yv = bf2f(*(const unsigned short*)(AlB + row * 512 +
                    (((c >> 3) ^ (row & 7)) << 4) + ((c & 7) << 1)));
                a2 = fmaf(yv, Wcol[c * 8], a2);
            }
            Y12g[((size_t)z * SY_ + row) * 16 + j] = a2;
        }
    }
}

// ---------------------------------------------------------------------------
// Merged: f32->bf16 convert of x (blocks 0..2047, grid-stride) +
// embeds gather (blocks 2048..4287, 8 rows each).
// ---------------------------------------------------------------------------
__global__ __launch_bounds__(256)
void conv_x_embed(const float* __restrict__ in, unsigned short* __restrict__ out,
                  int n8, const float* __restrict__ embeds,
                  const int* __restrict__ tgt_y, unsigned short* __restrict__ yb)
{
    if (blockIdx.x < 2048) {
        for (int i = blockIdx.x * 256 + threadIdx.x; i < n8; i += 2048 * 256) {
            float4 a = ((const float4*)in)[i * 2];
            float4 b = ((const float4*)in)[i * 2 + 1];
            us8 o = { f2bf(a.x), f2bf(a.y), f2bf(a.z), f2bf(a.w),
                      f2bf(b.x), f2bf(b.y), f2bf(b.z), f2bf(b.w) };
            ((us8*)out)[i] = o;
        }
    } else {
        const int i = (blockIdx.x - 2048) * 8 + (threadIdx.x >> 5);
        const int c8 = (threadIdx.x & 31) * 8;
        const int v = tgt_y[i];
        const float* p = embeds + (size_t)v * 256 + c8;
        float4 a = *(const float4*)p;
        float4 b = *(const float4*)(p + 4);
        us8 o = { f2bf(a.x), f2bf(a.y), f2bf(a.z), f2bf(a.w),
                  f2bf(b.x), f2bf(b.y), f2bf(b.z), f2bf(b.w) };
        *(us8*)(yb + (size_t)i * 256 + c8) = o;
    }
}

// ---------------------------------------------------------------------------
// All weight transposes in ONE dispatch. Grid (8, 8, 10); out-of-range exit.
// ---------------------------------------------------------------------------
struct WAll {
    const float* src[10];
    unsigned short* dst[10];
    int R[10];
    int C[10];
};

__global__ __launch_bounds__(256)
void conv_wT_all(WAll d)
{
    const int z = blockIdx.z;
    const int R = d.R[z], C = d.C[z];
    const int c0 = blockIdx.x * 64, r0 = blockIdx.y * 64;
    if (c0 >= C || r0 >= R) return;
    const float* in = d.src[z];
    unsigned short* outT = d.dst[z];
    __shared__ unsigned short t[64][65];
    const int r = threadIdx.x >> 4, cq = (threadIdx.x & 15) << 2;
#pragma unroll
    for (int i = 0; i < 4; ++i) {
        const int rr = r + i * 16;
        float4 v = *(const float4*)(in + (size_t)(r0 + rr) * C + c0 + cq);
        t[rr][cq + 0] = f2bf(v.x); t[rr][cq + 1] = f2bf(v.y);
        t[rr][cq + 2] = f2bf(v.z); t[rr][cq + 3] = f2bf(v.w);
    }
    __syncthreads();
    const int c = threadIdx.x >> 2, sq = (threadIdx.x & 3) << 4;
    us8 o0, o1;
#pragma unroll
    for (int i = 0; i < 8; ++i) { o0[i] = t[sq + i][c]; o1[i] = t[sq + 8 + i][c]; }
    *(us8*)(outT + (size_t)(c0 + c) * R + r0 + sq) = o0;
    *(us8*)(outT + (size_t)(c0 + c) * R + r0 + sq + 8) = o1;
}

// ---------------------------------------------------------------------------
// CSR build (4 small parallel dispatches — proven fast)
// ---------------------------------------------------------------------------
__global__ __launch_bounds__(256)
void edge_deg(const int* __restrict__ tgt, int* __restrict__ deg)
{
    const int e = blockIdx.x * 256 + threadIdx.x;
    if (e < NE_) atomicAdd(&deg[tgt[e]], 1);
}

__global__ __launch_bounds__(1024)
void scan_off(const int* __restrict__ deg, int* __restrict__ off, int* __restrict__ cursor)
{
    __shared__ int ls[1024];
    const int t = threadIdx.x;
    const int base = t * 18;
    int local[18];
    int s = 0;
#pragma unroll
    for (int i = 0; i < 18; ++i) {
        const int idx = base + i;
        const int v = (idx < NY_) ? deg[idx] : 0;
        local[i] = s; s += v;
    }
    ls[t] = s;
    __syncthreads();
    for (int d = 1; d < 1024; d <<= 1) {
        int v = (t >= d) ? ls[t - d] : 0;
        __syncthreads();
        ls[t] += v;
        __syncthreads();
    }
    const int excl = (t == 0) ? 0 : ls[t - 1];
#pragma unroll
    for (int i = 0; i < 18; ++i) {
        const int idx = base + i;
        if (idx < NY_) {
            const int o = excl + local[i];
            off[idx] = o; cursor[idx] = o;
        }
    }
    if (t == 1023) off[NY_] = ls[1023];
}

__global__ __launch_bounds__(256)
void edge_fill(const int* __restrict__ tgt, int* __restrict__ cursor,
               int* __restrict__ elist)
{
    const int e = blockIdx.x * 256 + threadIdx.x;
    if (e >= NE_) return;
    const int pos = atomicAdd(&cursor[tgt[e]], 1);
    elist[pos] = e;
}

// ---------------------------------------------------------------------------
// aggb[t,:] = bf16( hb[t,:] + sum_{e in bucket(t)} hb[src[e],:] + cnt * Ee )
// ---------------------------------------------------------------------------
__global__ __launch_bounds__(256)
void node_agg(const unsigned short* __restrict__ hb,
              const float* __restrict__ Ee,
              const int* __restrict__ src, const int* __restrict__ etype,
              const int* __restrict__ off, const int* __restrict__ elist,
              unsigned short* __restrict__ aggb)
{
    const int nid  = blockIdx.x * 4 + (threadIdx.x >> 6);
    const int lane = threadIdx.x & 63;
    const int c = lane * 4;
    const int k0 = off[nid], k1 = off[nid + 1];
    us4 sv = *(const us4*)(hb + (size_t)nid * 256 + c);
    float4 acc;
    acc.x = bf2f(sv[0]); acc.y = bf2f(sv[1]);
    acc.z = bf2f(sv[2]); acc.w = bf2f(sv[3]);
    int cnt0 = 0, cnt1 = 0, cnt2 = 0, cnt3 = 0;
    for (int k = k0; k < k1; ++k) {
        const int e = elist[k];
        const int sfrom = src[e];
        const int ty = etype[e];
        us4 hv = *(const us4*)(hb + (size_t)sfrom * 256 + c);
        acc.x += bf2f(hv[0]); acc.y += bf2f(hv[1]);
        acc.z += bf2f(hv[2]); acc.w += bf2f(hv[3]);
        cnt0 += (ty == 0); cnt1 += (ty == 1); cnt2 += (ty == 2); cnt3 += (ty == 3);
    }
    float4 e0 = *(const float4*)(Ee + c);
    float4 e1 = *(const float4*)(Ee + 256 + c);
    float4 e2 = *(const float4*)(Ee + 512 + c);
    float4 e3 = *(const float4*)(Ee + 768 + c);
    acc.x += cnt0 * e0.x + cnt1 * e1.x + cnt2 * e2.x + cnt3 * e3.x;
    acc.y += cnt0 * e0.y + cnt1 * e1.y + cnt2 * e2.y + cnt3 * e3.y;
    acc.z += cnt0 * e0.z + cnt1 * e1.z + cnt2 * e2.z + cnt3 * e3.z;
    acc.w += cnt0 * e0.w + cnt1 * e1.w + cnt2 * e2.w + cnt3 * e3.w;
    us4 o = { f2bf(acc.x), f2bf(acc.y), f2bf(acc.z), f2bf(acc.w) };
    *(us4*)(aggb + (size_t)nid * 256 + c) = o;
}

// ---------------------------------------------------------------------------
// esc[e,0:8] = Y12[src[e],0:8] + Y12[tgt[e],8:16] + b
// ---------------------------------------------------------------------------
__global__ __launch_bounds__(256)
void edge_gather(const float* __restrict__ Y12, const int* __restrict__ src,
                 const int* __restrict__ tgt, const float* __restrict__ bias,
                 float* __restrict__ esc)
{
    const int e = blockIdx.x * 256 + threadIdx.x;
    if (e >= NE_) return;
    const float* a = Y12 + (size_t)src[e] * 16;
    const float* b = Y12 + (size_t)tgt[e] * 16 + 8;
    float4 a0 = ((const float4*)a)[0], a1 = ((const float4*)a)[1];
    float4 b0 = ((const float4*)b)[0], b1 = ((const float4*)b)[1];
    float4 c0 = ((const float4*)bias)[0], c1 = ((const float4*)bias)[1];
    float4 o0, o1;
    o0.x = a0.x + b0.x + c0.x; o0.y = a0.y + b0.y + c0.y;
    o0.z = a0.z + b0.z + c0.z; o0.w = a0.w + b0.w + c0.w;
    o1.x = a1.x + b1.x + c1.x; o1.y = a1.y + b1.y + c1.y;
    o1.z = a1.z + b1.z + c1.z; o1.w = a1.w + b1.w + c1.w;
    ((float4*)(esc + (size_t)e * 8))[0] = o0;
    ((float4*)(esc + (size_t)e * 8))[1] = o1;
}

// ---------------------------------------------------------------------------
extern "C" void kernel_launch(void* const* d_in, const int* in_sizes, int n_in,
                              void* d_out, int out_size, void* d_ws, size_t ws_size,
                              hipStream_t stream)
{
    const float* x       = (const float*)d_in[0];
    const int*   tgt_y   = (const int*)d_in[2];
    const int*   eidx    = (const int*)d_in[3];
    const int*   etype   = (const int*)d_in[4];
    const float* embeds  = (const float*)d_in[6];
    const float* W_in[3] = {(const float*)d_in[7],  (const float*)d_in[11], (const float*)d_in[15]};
    const float* Wq[3]   = {(const float*)d_in[8],  (const float*)d_in[12], (const float*)d_in[16]};
    const float* Wv[3]   = {(const float*)d_in[9],  (const float*)d_in[13], (const float*)d_in[17]};
    const float* Ee[3]   = {(const float*)d_in[10], (const float*)d_in[14], (const float*)d_in[18]};
    const float* lin_z_w = (const float*)d_in[19];
    const float* lin_z_b = (const float*)d_in[20];
    const float* lin_g_w = (const float*)d_in[21];
    const float* lin_g_b = (const float*)d_in[22];
    const int* src = eidx;
    const int* tgt = eidx + NE_;

    float* out = (float*)d_out;
    // d_out layout (floats)
    float* y_final = out;                        // [17920][256]
    float* score   = out + 4587520;              // [17920][256]
    float* esc     = out + 9175040;              // [71680][8]
    float* aout[3] = {out + 9748480, out + 14336000, out + 18923520}; // [B][70][256]

    // workspace layout (bytes)
    char* wsb = (char*)d_ws;
    unsigned short* xb     = (unsigned short*)(wsb + 0);            //  67,108,864
    unsigned short* xvTall = (unsigned short*)(wsb + 67108864);     // 100,663,296  [B][768][256]
    unsigned short* hb     = (unsigned short*)(wsb + 167772160);    //   9,175,040
    unsigned short* aggb   = (unsigned short*)(wsb + 176947200);    //   9,175,040
    unsigned short* qb     = (unsigned short*)(wsb + 186122240);    //  18,350,080
    unsigned short* yb     = (unsigned short*)(wsb + 204472320);    //   9,175,040
    char* wt = wsb + 213647360;                                     //   2,883,584
    // wcatT[l]: [768][256] bf16 (rows 0-255 = W_in^T, rows 256-767 = (W_in@Wq)^T)
    unsigned short* wcatT[3], *wqT[3], *wvT[3];
    for (int l = 0; l < 3; ++l) {
        wcatT[l] = (unsigned short*)(wt + l * 393216);
        wqT[l]   = (unsigned short*)(wt + 1179648 + l * 262144);
        wvT[l]   = (unsigned short*)(wt + 1966080 + l * 262144);  // contiguous x3 = [768][512]
    }
    unsigned short* lzT = (unsigned short*)(wt + 2752512);
    char* extra = wsb + 216530944;
    float* Y12    = (float*)extra;                 // 1,146,880
    int*   deg    = (int*)(extra + 1146880);       //    71,680
    int*   off    = (int*)(extra + 1218560);       //    71,684
    int*   cursor = (int*)(extra + 1290244);       //    71,680
    int*   elist  = (int*)(extra + 1361924);       //   286,720

    // --- CSR build (parallel 4-dispatch pipeline) ---
    hipMemsetAsync(deg, 0, NY_ * sizeof(int), stream);
    edge_deg<<<280, 256, 0, stream>>>(tgt, deg);
    scan_off<<<1, 1024, 0, stream>>>(deg, off, cursor);
    edge_fill<<<280, 256, 0, stream>>>(tgt, cursor, elist);

    // --- one-time conversions ---
    conv_x_embed<<<4288, 256, 0, stream>>>(x, xb, 4194304, embeds, tgt_y, yb);
    WAll wd;
    for (int l = 0; l < 3; ++l) {
        wd.src[l]     = W_in[l]; wd.dst[l]     = wcatT[l]; wd.R[l]     = 256; wd.C[l]     = 256;
        wd.src[3 + l] = Wq[l];   wd.dst[3 + l] = wqT[l];   wd.R[3 + l] = 256; wd.C[3 + l] = 512;
        wd.src[6 + l] = Wv[l];   wd.dst[6 + l] = wvT[l];   wd.R[6 + l] = 512; wd.C[6 + l] = 256;
    }
    wd.src[9] = lin_z_w; wd.dst[9] = lzT; wd.R[9] = 256; wd.C[9] = 256;
    conv_wT_all<<<dim3(8, 8, 10), 256, 0, stream>>>(wd);

    // --- wcatT rows 256-767 = (W_in@Wq)^T = Wq^T @ W_in^T  (batched z=3) ---
    gemm_mfma<0, 0><<<dim3(2, 4, 3), 256, 0, stream>>>(
        wqT[0], 256, 131072L,  wcatT[0], 256, 196608L,
        nullptr, 0, 0,  wcatT[0] + 65536, 256, 196608L,
        nullptr, 0, 512, 256, 1.f, 0, 0);

    // --- xvTall[b] = [Wv1;Wv2;Wv3]^T-concat @ x_b^T : [768][256] per batch ---
    gemm_mfma<0, 1><<<3072, 256, 0, stream>>>(
        wvT[0], 512, 0,  xb, 512, (long)SX_ * F_,
        nullptr, 0, 0,  xvTall, 256, 768L * 256,
        nullptr, 0, 768, 512, 1.f, 2, 6);

    const float qscale = 0.044194173824159216f;  // 1/sqrt(512)
    for (int l = 0; l < 3; ++l) {
        // [h|q] = y @ Wcat : cols 0-255 -> hb (bf16), cols 256-767 -> qb (bf16)
        gemm_mfma<7, 0><<<dim3(6, 140, 1), 256, 0, stream>>>(
            yb, 256, 0,  wcatT[l], 256, 0,
            (float*)qb, 512, 0,  hb, 256, 0,
            nullptr, 0, NY_, 256, 1.f, 0, 0);
        // aggb = bf16(h + segment_sum(h[src] + Ee[etype], tgt))
        node_agg<<<4480, 256, 0, stream>>>(hb, Ee[l], src, etype, off, elist, aggb);
        // fused attn: logits+softmax -> alpha; PV + relu (+ score, Y12 on last)
        if (l < 2) {
            attn_pv<0><<<256, 512, 0, stream>>>(
                qb, xb, xvTall + (size_t)l * 65536, 768L * 256,
                aggb, nullptr, nullptr, nullptr, nullptr,
                aout[l], yb, nullptr, nullptr, qscale);
        } else {
            attn_pv<1><<<256, 512, 0, stream>>>(
                qb, xb, xvTall + (size_t)l * 65536, 768L * 256,
                aggb, lzT, lin_z_b, lin_g_w, Y12,
                aout[l], yb, y_final, score, qscale);
        }
    }
    // edge relation scores from Y12
    edge_gather<<<280, 256, 0, stream>>>(Y12, src, tgt, lin_g_b, esc);
}